// Round 8
// baseline (1132.060 us; speedup 1.0000x reference)
//
#include <hip/hip_runtime.h>
#include <math.h>

#define NN 50000
#define FINN 64
#define HD 128
#define EE 800000
#define TT 8
#define PP 250000
#define DD 500000
#define GG 20000
#define VV 2000
#define OO 2

#define DEC_GRID 256
#define DEC_TILES ((PP + 63) / 64)

typedef short short8 __attribute__((ext_vector_type(8)));
typedef float f32x4 __attribute__((ext_vector_type(4)));

__device__ __forceinline__ unsigned short f2bf(float f) {
    unsigned int u = __float_as_uint(f);
    u += 0x7fffu + ((u >> 16) & 1u);   // round-to-nearest-even
    return (unsigned short)(u >> 16);
}
__device__ __forceinline__ float bf2f(unsigned short u) {
    return __uint_as_float(((unsigned int)u) << 16);
}

// f32 -> fp8 e4m3fn (via bf16, RTNE, denorm-flush, NaN-guarded clamp)
__device__ __forceinline__ unsigned char q8(float f) {
    unsigned short u = f2bf(f);
    unsigned int e = (u >> 7) & 0xffu;
    unsigned int s = (u >> 8) & 0x80u;
    if (e < 121u) return (unsigned char)s;      // |v| < 2^-6 -> +-0
    unsigned int m = u & 0x7fu;
    unsigned int m3 = m >> 4, rr = m & 0xfu;
    m3 += (rr > 8u) || (rr == 8u && (m3 & 1u));
    unsigned int ee = e - 120u;
    if (m3 == 8u) { m3 = 0u; ++ee; }
    if (ee > 15u || (ee == 15u && m3 == 7u)) { ee = 15u; m3 = 6u; }  // clamp 448, avoid NaN
    return (unsigned char)(s | (ee << 3) | m3);
}
// fp8 byte -> bf16 bits (denormals were flushed at encode)
__device__ __forceinline__ unsigned int dq1(unsigned int b) {
    unsigned int t = b & 0x7fu;
    unsigned int r = ((b & 0x80u) << 8) | ((t << 4) + 0x3C00u);
    return t ? r : 0u;
}
__device__ __forceinline__ short8 dq8(unsigned long long v) {
    short8 o;
#pragma unroll
    for (int j = 0; j < 8; ++j)
        o[j] = (short)dq1((unsigned int)(v >> (8 * j)) & 0xffu);
    return o;
}

struct us8 { unsigned short v[8]; };

__device__ __forceinline__ void gload_lds16(const void* g, void* l) {
    __builtin_amdgcn_global_load_lds((__attribute__((address_space(1))) void*)g,
                                     (__attribute__((address_space(3))) void*)l, 16, 0, 0);
}

// ------------------------------------------------------------------
__global__ void count_k(const int* __restrict__ idx, int* __restrict__ counts, int n) {
    int i = blockIdx.x * blockDim.x + threadIdx.x;
    if (i < n) atomicAdd(&counts[idx[i]], 1);
}

__global__ void blk_sum_k(const int* __restrict__ counts, int n, int* __restrict__ bsum) {
    __shared__ int buf[256];
    int t = threadIdx.x, i = blockIdx.x * 256 + t;
    buf[t] = (i < n) ? counts[i] : 0;
    __syncthreads();
    for (int off = 128; off > 0; off >>= 1) {
        if (t < off) buf[t] += buf[t + off];
        __syncthreads();
    }
    if (t == 0) bsum[blockIdx.x] = buf[0];
}

__global__ void scan_small_k(const int* __restrict__ bsum, int nb, int* __restrict__ boff) {
    __shared__ int buf[256];
    int t = threadIdx.x;
    int v = (t < nb) ? bsum[t] : 0;
    buf[t] = v;
    __syncthreads();
    for (int off = 1; off < 256; off <<= 1) {
        int u = (t >= off) ? buf[t - off] : 0;
        __syncthreads();
        buf[t] += u;
        __syncthreads();
    }
    if (t < nb) boff[t] = buf[t] - v;
}

__global__ void rowptr_fill_k(const int* __restrict__ counts, const int* __restrict__ boff,
                              int n, int* __restrict__ rowptr, int total) {
    __shared__ int buf[256];
    int t = threadIdx.x, i = blockIdx.x * 256 + t;
    int v = (i < n) ? counts[i] : 0;
    buf[t] = v;
    __syncthreads();
    for (int off = 1; off < 256; off <<= 1) {
        int u = (t >= off) ? buf[t - off] : 0;
        __syncthreads();
        buf[t] += u;
        __syncthreads();
    }
    if (i < n) rowptr[i] = boff[blockIdx.x] + buf[t] - v;
    if (i == 0) rowptr[n] = total;
}

__global__ void lb_rowptr_k(const int* __restrict__ arr, int n, int* __restrict__ rowptr, int m) {
    int i = blockIdx.x * blockDim.x + threadIdx.x;
    if (i > m) return;
    int lo = 0, hi = n;
    while (lo < hi) {
        int mid = (lo + hi) >> 1;
        if (arr[mid] < i) lo = mid + 1; else hi = mid;
    }
    rowptr[i] = lo;
}

__global__ void fill_csr_k(const int* __restrict__ esrc, const int* __restrict__ edst,
                           const int* __restrict__ rowptr, int* __restrict__ cursor,
                           int* __restrict__ outi, int n) {
    int e = blockIdx.x * blockDim.x + threadIdx.x;
    if (e < n) {
        int d = edst[e];
        int pos = atomicAdd(&cursor[d], 1);
        outi[rowptr[d] + pos] = esrc[e];
    }
}

// ------------------------------------------------------------------
__global__ void hist9_k(const int* __restrict__ t_idx, int* __restrict__ hist) {
    __shared__ int l[9];
    if (threadIdx.x < 9) l[threadIdx.x] = 0;
    __syncthreads();
    int p = blockIdx.x * 256 + threadIdx.x;
    if (p < PP) atomicAdd(&l[t_idx[p]], 1);
    __syncthreads();
    if (threadIdx.x < 9) atomicAdd(&hist[threadIdx.x], l[threadIdx.x]);
}

__global__ void scan9_k(const int* __restrict__ hist, int* __restrict__ boff9) {
    if (threadIdx.x == 0) {
        int a = 0;
        for (int i = 0; i < 9; ++i) { boff9[i] = a; a += hist[i]; }
        boff9[9] = a;
    }
}

__global__ void bucket_perm_k(const int* __restrict__ t_idx, const int* __restrict__ boff9,
                              int* __restrict__ cursor9, int* __restrict__ pperm) {
    __shared__ int lcnt[9];
    __shared__ int lbase[9];
    int tid = threadIdx.x;
    int p = blockIdx.x * 256 + tid;
    if (tid < 9) lcnt[tid] = 0;
    __syncthreads();
    int t = 0, lr = 0;
    bool ok = p < PP;
    if (ok) {
        t = t_idx[p];
        lr = atomicAdd(&lcnt[t], 1);
    }
    __syncthreads();
    if (tid < 9) lbase[tid] = atomicAdd(&cursor9[tid], lcnt[tid]);
    __syncthreads();
    if (ok) pperm[boff9[t] + lbase[t] + lr] = p;
}

// ------------------------------------------------------------------
__global__ void prep_k(const float* __restrict__ x,
                       const float* __restrict__ Wes, const float* __restrict__ Wen,
                       const float* __restrict__ W2s, const float* __restrict__ W2n,
                       const float* __restrict__ Wd1,
                       unsigned short* __restrict__ xb, unsigned short* __restrict__ wenc_t,
                       unsigned short* __restrict__ w2_t, unsigned short* __restrict__ wd1t) {
    int i = blockIdx.x * 256 + threadIdx.x;
    if (i < NN * FINN) xb[i] = f2bf(x[i]);
    if (i < HD * 2 * FINN) {
        int c = i / (2 * FINN), k = i - c * (2 * FINN);
        wenc_t[i] = f2bf((k < FINN) ? Wes[k * HD + c] : Wen[(k - FINN) * HD + c]);
    }
    if (i < HD * 2 * HD) {
        int c = i / (2 * HD), k = i - c * (2 * HD);
        w2_t[i] = f2bf((k < HD) ? W2s[k * HD + c] : W2n[(k - HD) * HD + c]);
    }
    if (i < 384 * 384) {
        int n = i / 384, k = i - n * 384;
        wd1t[i] = f2bf(Wd1[k * 384 + n]);
    }
}

// ------------------------------------------------------------------
// mpf: fused mean-agg + MFMA round (depth-2 gather -- R4-proven best).
// Also emits fp8 shadow of the output (houtq, rows of 128 bytes).
template <int KIN>
__launch_bounds__(256)
__global__ void mpf_k(const unsigned short* __restrict__ hin,
                      const int* __restrict__ rowptr, const int* __restrict__ csr_src,
                      const unsigned short* __restrict__ Wt, const float* __restrict__ bias,
                      unsigned short* __restrict__ hout, unsigned char* __restrict__ houtq) {
    constexpr int CPL = KIN / 64;
    __shared__ unsigned short sm[32 * KIN];
    int tid = threadIdx.x;
    int r = tid >> 3;
    int sl = tid & 7;
    int node = blockIdx.x * 32 + r;
    int rx = r & 7;

    if (node < NN) {
        int s = rowptr[node], e = rowptr[node + 1];
        float acc[8 * CPL] = {};
        int i = s, iB = s + 1;
        int srcA = (i < e) ? csr_src[i] : 0;
        int srcB = (iB < e) ? csr_src[iB] : 0;
        while (i < e) {
            bool hB = iB < e;
            us8 vA0, vA1, vB0, vB1;
            vA0 = *(const us8*)&hin[(size_t)srcA * KIN + sl * (8 * CPL)];
            if constexpr (CPL == 2) vA1 = *(const us8*)&hin[(size_t)srcA * KIN + sl * 16 + 8];
            if (hB) {
                vB0 = *(const us8*)&hin[(size_t)srcB * KIN + sl * (8 * CPL)];
                if constexpr (CPL == 2) vB1 = *(const us8*)&hin[(size_t)srcB * KIN + sl * 16 + 8];
            }
            int iN = i + 2, iN2 = i + 3;
            srcA = (iN < e) ? csr_src[iN] : 0;
            srcB = (iN2 < e) ? csr_src[iN2] : 0;
#pragma unroll
            for (int j = 0; j < 8; ++j) acc[j] += bf2f(vA0.v[j]);
            if constexpr (CPL == 2)
#pragma unroll
                for (int j = 0; j < 8; ++j) acc[8 + j] += bf2f(vA1.v[j]);
            if (hB) {
#pragma unroll
                for (int j = 0; j < 8; ++j) acc[j] += bf2f(vB0.v[j]);
                if constexpr (CPL == 2)
#pragma unroll
                    for (int j = 0; j < 8; ++j) acc[8 + j] += bf2f(vB1.v[j]);
            }
            i = iN; iB = iN2;
        }
        float d = fmaxf((float)(e - s), 1.f);
        us8 o0, o1;
#pragma unroll
        for (int j = 0; j < 8; ++j) o0.v[j] = f2bf(acc[j] / d);
        int c0 = sl * CPL;
        *(us8*)&sm[r * KIN + ((c0 ^ rx) * 8)] = o0;
        if constexpr (CPL == 2) {
#pragma unroll
            for (int j = 0; j < 8; ++j) o1.v[j] = f2bf(acc[8 + j] / d);
            *(us8*)&sm[r * KIN + (((c0 + 1) ^ rx) * 8)] = o1;
        }
    }
    __syncthreads();

    // ---- phase B: MFMA ----
    int lane = tid & 63, w = tid >> 6;
    int cc = lane & 15, gq = lane >> 4;
    constexpr int K = 2 * KIN;
    int rloc = (w & 1) * 16 + cc;
    int rowA = blockIdx.x * 32 + rloc;
    bool rowok = rowA < NN;
    const unsigned short* hrow = hin + (size_t)rowA * KIN;
    int ch = (w >> 1) * 64;
    int rlx = rloc & 7;

    f32x4 acc2[4];
#pragma unroll
    for (int t = 0; t < 4; ++t) acc2[t] = (f32x4){0.f, 0.f, 0.f, 0.f};

#pragma unroll
    for (int k0 = 0; k0 < K; k0 += 32) {
        int k = k0 + gq * 8;
        short8 a = {0, 0, 0, 0, 0, 0, 0, 0};
        if (rowok) {
            if (k0 < KIN) a = *(const short8*)(hrow + k);
            else {
                int chunk = (k - KIN) >> 3;
                a = *(const short8*)&sm[rloc * KIN + ((chunk ^ rlx) * 8)];
            }
        }
#pragma unroll
        for (int t = 0; t < 4; ++t) {
            short8 b = *(const short8*)&Wt[(size_t)(ch + t * 16 + cc) * K + k];
            acc2[t] = __builtin_amdgcn_mfma_f32_16x16x32_bf16(a, b, acc2[t], 0, 0, 0);
        }
    }
#pragma unroll
    for (int t = 0; t < 4; ++t) {
        int col = ch + t * 16 + cc;
        float b1 = bias[col];
#pragma unroll
        for (int rj = 0; rj < 4; ++rj) {
            int grow = blockIdx.x * 32 + (w & 1) * 16 + gq * 4 + rj;
            if (grow < NN) {
                float v = fmaxf(acc2[t][rj] + b1, 0.f);
                hout[(size_t)grow * HD + col] = f2bf(v);
                houtq[(size_t)grow * HD + col] = q8(v);
            }
        }
    }
}

// ------------------------------------------------------------------
// dst segment-sum (monolithic, fp8 gather 128B rows, fp8 output).
__launch_bounds__(256)
__global__ void dst_sum2q_k(const unsigned char* __restrict__ featsq,
                            const int* __restrict__ t_idx, const int* __restrict__ dst_nodes,
                            const int* __restrict__ dst_rowptr, const int* __restrict__ pperm,
                            unsigned char* __restrict__ dstcq) {
    int tid = threadIdx.x;
    int grp = tid >> 4;
    int fl = tid & 15;
    int pi = blockIdx.x * 16 + grp;
    if (pi >= PP) return;
    int p = pperm[pi];
    long t = t_idx[p];
    const unsigned char* base = featsq + (size_t)t * NN * HD;
    int s = dst_rowptr[p], e = dst_rowptr[p + 1];
    float acc[8] = {};
    int i = s;
    int n0 = (i < e) ? dst_nodes[i] : 0;
    int n1 = (i + 1 < e) ? dst_nodes[i + 1] : 0;
    while (i < e) {
        bool h1 = (i + 1) < e;
        unsigned long long v0 = *(const unsigned long long*)&base[(size_t)n0 * HD + fl * 8];
        unsigned long long v1 = 0;
        if (h1) v1 = *(const unsigned long long*)&base[(size_t)n1 * HD + fl * 8];
        int i2 = i + 2, i3 = i + 3;
        n0 = (i2 < e) ? dst_nodes[i2] : 0;
        n1 = (i3 < e) ? dst_nodes[i3] : 0;
#pragma unroll
        for (int j = 0; j < 8; ++j)
            acc[j] += bf2f((unsigned short)dq1((unsigned int)(v0 >> (8 * j)) & 0xffu));
        if (h1) {
#pragma unroll
            for (int j = 0; j < 8; ++j)
                acc[j] += bf2f((unsigned short)dq1((unsigned int)(v1 >> (8 * j)) & 0xffu));
        }
        i = i2;
    }
    unsigned long long ov = 0;
#pragma unroll
    for (int j = 0; j < 8; ++j) ov |= (unsigned long long)q8(acc[j]) << (8 * j);
    *(unsigned long long*)&dstcq[(size_t)pi * HD + fl * 8] = ov;
}

// ------------------------------------------------------------------
// dec9: dec7 pipeline with fp8 A-panel (half the gather bytes/requests).
// Rows 128B; 24KB panel x3; 3 gload_lds per wave per stage; VALU dequant
// fp8->bf16 before the (unchanged) bf16 MFMA with breg-resident B.
// Counted vmcnt re-derived for new per-wave op counts (A=5, S=3, OUT=4):
// steady 16 (exact for non-OUT waves; OUT waves over-wait 1-iter-old
// stores/loads only), k<2: 11, nt-2: 13, nt-1: 5.
__global__ void
__attribute__((amdgpu_flat_work_group_size(512, 512), amdgpu_waves_per_eu(2, 2)))
dec9_k(const unsigned char* __restrict__ featsq,
       const unsigned char* __restrict__ dstcq,
       const int* __restrict__ place_idx, const int* __restrict__ src_idx,
       const int* __restrict__ t_idx, const int* __restrict__ group_id,
       const int* __restrict__ pperm,
       const unsigned short* __restrict__ Wd1t,
       const float* __restrict__ bd1, const float* __restrict__ Wd2,
       const float* __restrict__ bd2, float* __restrict__ logprob,
       float* __restrict__ group_sums) {
    __shared__ unsigned char buf[3][192 * 128];      // 3 x 24 KB fp8 A-panels
    __shared__ unsigned int rb[3][192];              // byte offsets from featsq
    __shared__ float lpart[3][8][64][2];

    int tid = threadIdx.x;
    int lane = tid & 63, w = tid >> 6;               // 8 waves
    int cc = lane & 15, gq = lane >> 4;
    int bid = blockIdx.x;

    int row = min(tid, 191);
    int sec = row >> 6, pl = row & 63;
    const int* nptr = (sec == 0) ? place_idx : src_idx;
    unsigned int dstc_off = (unsigned int)(dstcq - featsq);

    int nt = (DEC_TILES - 1 - bid) / DEC_GRID + 1;   // >= 15
    float b20 = bd2[0], b21 = bd2[1];

    // ---- prologue: rb for tiles 0..2, chase regs, hoisted consts ----
    if (tid < 192) {
#pragma unroll
        for (int s3 = 0; s3 < 3; ++s3) {
            int pic = min((bid + s3 * DEC_GRID) * 64 + pl, PP - 1);
            int p = pperm[pic];
            rb[s3][tid] = (sec == 2) ? (dstc_off + (unsigned int)pic * 128u)
                                     : (unsigned int)(((unsigned)t_idx[p] * NN + (unsigned)nptr[p]) * 128u);
        }
    }
    int p3 = pperm[min((bid + 3 * DEC_GRID) * 64 + pl, PP - 1)];
    int tOld = t_idx[p3], nOld = nptr[p3];
    int pCur = pperm[min((bid + 4 * DEC_GRID) * 64 + pl, PP - 1)];
    int opPP = 0, opP = 0, ogP = 0;

    short8 breg[36];
    float b1r[3], w0r[3], w1r[3];
    {
        const unsigned short* bbase = Wd1t + ((long)(w * 48 + cc) * 384 + gq * 8);
#pragma unroll
        for (int kk = 0; kk < 12; ++kk)
#pragma unroll
            for (int t = 0; t < 3; ++t)
                breg[kk * 3 + t] = *(const short8*)(bbase + (long)t * 16 * 384 + kk * 32);
#pragma unroll
        for (int t = 0; t < 3; ++t) {
            int col = w * 48 + t * 16 + cc;
            b1r[t] = bd1[col];
            w0r[t] = Wd2[col * 2 + 0];
            w1r[t] = Wd2[col * 2 + 1];
        }
    }
    __syncthreads();   // full drain once

    int rsub8 = lane >> 3, chunk8 = lane & 7;

#define STAGE(slot_)                                                                 \
    {                                                                                \
        _Pragma("unroll")                                                            \
        for (int i = 0; i < 3; ++i) {                                                \
            int r = w * 24 + i * 8 + rsub8;                                          \
            const unsigned char* src = featsq + rb[slot_][r] +                       \
                                       ((unsigned)(chunk8 ^ (r & 7)) << 4);          \
            gload_lds16(src, &buf[slot_][(w * 24 + i * 8) * 128]);                   \
        }                                                                            \
    }

#define OUTPUT(tile_, slot_, opv_, ogv_)                                             \
    {                                                                                \
        int pi = (bid + (tile_) * DEC_GRID) * 64 + w * 16 + cc;                      \
        if (pi < PP) {                                                               \
            float l0 = b20, l1 = b21;                                                \
            _Pragma("unroll")                                                        \
            for (int w2 = 0; w2 < 8; ++w2) {                                         \
                l0 += lpart[slot_][w2][w * 16 + cc][0];                              \
                l1 += lpart[slot_][w2][w * 16 + cc][1];                              \
            }                                                                        \
            float mm = fmaxf(l0, l1);                                                \
            float lse = mm + logf(expf(l0 - mm) + expf(l1 - mm));                    \
            float lp0 = l0 - lse, lp1 = l1 - lse;                                    \
            logprob[(opv_)*2 + 0] = lp0;                                             \
            logprob[(opv_)*2 + 1] = lp1;                                             \
            atomicAdd(&group_sums[(ogv_)*2 + 0], lp0);                               \
            atomicAdd(&group_sums[(ogv_)*2 + 1], lp1);                               \
        }                                                                            \
    }

    STAGE(0);
    STAGE(1);

    for (int k = 0; k < nt; ++k) {
        int slot = k % 3;

        // ---- A-phase: 5 idx loads, consumed >=1 iter later ----
        int opN = pperm[min((bid + k * DEC_GRID) * 64 + (w & 3) * 16 + cc, PP - 1)];
        int ogN = group_id[opP];
        int pNew = pperm[min((bid + (k + 5) * DEC_GRID) * 64 + pl, PP - 1)];
        int tNew = t_idx[pCur];
        int nNew = nptr[pCur];
        __builtin_amdgcn_sched_barrier(0);

        // ---- stage tile k+2 (3 VMEM) ----
        if (k + 2 < nt) STAGE((k + 2) % 3);
        __builtin_amdgcn_sched_barrier(0);

        // ---- counted wait: S(k) complete, newer pipeline in flight ----
        if (k + 2 < nt) {
            if (k >= 2) { asm volatile("s_waitcnt vmcnt(16)" ::: "memory"); }
            else        { asm volatile("s_waitcnt vmcnt(11)" ::: "memory"); }
        } else if (k + 1 < nt) {
            asm volatile("s_waitcnt vmcnt(13)" ::: "memory");
        } else {
            asm volatile("s_waitcnt vmcnt(5)" ::: "memory");
        }
        __builtin_amdgcn_s_barrier();
        __builtin_amdgcn_sched_barrier(0);

        // ---- OUTPUT(k-2): stores + atomics only ----
        if (k >= 2 && w < 4 && lane < 16) OUTPUT(k - 2, (k - 2) % 3, opPP, ogP);

        // ---- compute tile k (zero VMEM; dequant fp8->bf16 in VALU) ----
        {
            const unsigned char* bufc = &buf[slot][0];
            f32x4 acc[4][3];
#pragma unroll
            for (int s = 0; s < 4; ++s)
#pragma unroll
                for (int t = 0; t < 3; ++t) acc[s][t] = (f32x4){0.f, 0.f, 0.f, 0.f};

#pragma unroll
            for (int kk = 0; kk < 12; ++kk) {
                int seck = kk >> 2;
                int eb = (kk & 3) * 32 + gq * 8;       // byte offset in row
                int c16 = eb >> 4, sub = (eb >> 3) & 1;
                short8 a_c[4];
#pragma unroll
                for (int s = 0; s < 4; ++s) {
                    int lrow = seck * 64 + s * 16 + cc;
                    unsigned long long v = *(const unsigned long long*)
                        &bufc[lrow * 128 + ((c16 ^ (lrow & 7)) << 4) + sub * 8];
                    a_c[s] = dq8(v);
                }
#pragma unroll
                for (int t = 0; t < 3; ++t)
#pragma unroll
                    for (int s = 0; s < 4; ++s)
                        acc[s][t] = __builtin_amdgcn_mfma_f32_16x16x32_bf16(
                            a_c[s], breg[kk * 3 + t], acc[s][t], 0, 0, 0);
            }

            // ---- epilogue per s ----
#pragma unroll
            for (int s = 0; s < 4; ++s) {
                float p0[4], p1[4];
#pragma unroll
                for (int r = 0; r < 4; ++r) { p0[r] = 0.f; p1[r] = 0.f; }
#pragma unroll
                for (int t = 0; t < 3; ++t) {
#pragma unroll
                    for (int r = 0; r < 4; ++r) {
                        float h = fmaxf(acc[s][t][r] + b1r[t], 0.f);
                        p0[r] += h * w0r[t];
                        p1[r] += h * w1r[t];
                    }
                }
#pragma unroll
                for (int m = 1; m < 16; m <<= 1)
#pragma unroll
                    for (int r = 0; r < 4; ++r) {
                        p0[r] += __shfl_xor(p0[r], m);
                        p1[r] += __shfl_xor(p1[r], m);
                    }
                if (cc == 0) {
#pragma unroll
                    for (int r = 0; r < 4; ++r) {
                        int orow = s * 16 + gq * 4 + r;
                        lpart[slot][w][orow][0] = p0[r];
                        lpart[slot][w][orow][1] = p1[r];
                    }
                }
            }
        }

        // ---- tail: rb for tile k+3 ----
        if (tid < 192) {
            int picw = min((bid + (k + 3) * DEC_GRID) * 64 + pl, PP - 1);
            rb[(k + 3) % 3][tid] = (sec == 2)
                ? (dstc_off + (unsigned int)picw * 128u)
                : (unsigned int)(((unsigned)tOld * NN + (unsigned)nOld) * 128u);
        }
        tOld = tNew; nOld = nNew; pCur = pNew;
        opPP = opP; opP = opN; ogP = ogN;

        asm volatile("s_waitcnt lgkmcnt(0)" ::: "memory");
        __builtin_amdgcn_s_barrier();
        __builtin_amdgcn_sched_barrier(0);
    }

    // ---- post-loop outputs ----
    if (w < 4 && lane < 16) {
        OUTPUT(nt - 2, (nt - 2) % 3, opPP, ogP);
        int ogLast = group_id[opP];
        OUTPUT(nt - 1, (nt - 1) % 3, opP, ogLast);
    }
#undef STAGE
#undef OUTPUT
}

// ------------------------------------------------------------------
__global__ void within_total_k(const float* __restrict__ group_sums,
                               const int* __restrict__ var_rowptr,
                               const float* __restrict__ counts,
                               float* __restrict__ within, float* __restrict__ total) {
    __shared__ float buf[256];
    int tid = threadIdx.x;
    float s = 0.f;
    for (int i = tid; i < VV; i += 256) s += counts[i];
    buf[tid] = s;
    __syncthreads();
    for (int off = 128; off > 0; off >>= 1) {
        if (tid < off) buf[tid] += buf[tid + off];
        __syncthreads();
    }
    if (tid == 0) total[0] = buf[0];
    for (int v = tid; v < VV; v += 256) {
        int gs = var_rowptr[v], ge = var_rowptr[v + 1];
        float r0 = 0.f, r1 = 0.f;
        for (int g = gs; g < ge; ++g) {
            r0 += group_sums[2 * g + 0];
            r1 += group_sums[2 * g + 1];
            within[2 * g + 0] = r0;
            within[2 * g + 1] = r1;
        }
    }
}

__global__ void final_k(const float* __restrict__ logprob, const float* __restrict__ within,
                        const int* __restrict__ group_id, const int* __restrict__ vog,
                        const float* __restrict__ counts, const float* __restrict__ total,
                        const int* __restrict__ place_idx, float* __restrict__ outp) {
    int p = blockIdx.x * blockDim.x + threadIdx.x;
    if (p >= PP) return;
    int g = group_id[p];
    int v = vog[g];
    float lc = logf(counts[v]) - logf(total[0]);
    int node = place_idx[p];
    atomicAdd(&outp[node * 2 + 0], logprob[p * 2 + 0] + within[g * 2 + 0] + lc);
    atomicAdd(&outp[node * 2 + 1], logprob[p * 2 + 1] + within[g * 2 + 1] + lc);
}

// ------------------------------------------------------------------
extern "C" void kernel_launch(void* const* d_in, const int* in_sizes, int n_in,
                              void* d_out, int out_size, void* d_ws, size_t ws_size,
                              hipStream_t stream) {
    const float* x          = (const float*)d_in[0];
    const float* W_enc_self = (const float*)d_in[1];
    const float* W_enc_nei  = (const float*)d_in[2];
    const float* b_enc      = (const float*)d_in[3];
    const float* W2_self    = (const float*)d_in[4];
    const float* W2_nei     = (const float*)d_in[5];
    const float* b2         = (const float*)d_in[6];
    const float* Wd1        = (const float*)d_in[7];
    const float* bd1        = (const float*)d_in[8];
    const float* Wd2        = (const float*)d_in[9];
    const float* bd2        = (const float*)d_in[10];
    const float* counts     = (const float*)d_in[11];
    const int* edge_src     = (const int*)d_in[12];
    const int* edge_dst     = (const int*)d_in[13];
    const int* place_idx    = (const int*)d_in[14];
    const int* src_idx      = (const int*)d_in[15];
    const int* t_idx        = (const int*)d_in[16];
    const int* dst_nodes    = (const int*)d_in[17];
    const int* dst_seg      = (const int*)d_in[18];
    const int* group_id     = (const int*)d_in[19];
    const int* variant_of_group = (const int*)d_in[20];
    float* outp = (float*)d_out;

    const int NB = (NN + 255) / 256;

    // ---- workspace layout (shrunk: rotating bf16 feats + fp8 shadows) ----
    unsigned short* rot0 = (unsigned short*)d_ws;               // N*H bf16
    unsigned short* rot1 = rot0 + (size_t)NN * HD;              // N*H bf16
    unsigned short* xb   = rot1 + (size_t)NN * HD;              // N*FIN bf16
    unsigned char* featsq = (unsigned char*)(xb + (size_t)NN * FINN);  // 9*N*128 fp8
    unsigned char* dstcq  = featsq + (size_t)(TT + 1) * NN * HD;       // P*128 fp8
    unsigned short* wenc_t = (unsigned short*)(dstcq + (size_t)PP * HD); // 128*128
    unsigned short* w2_t   = wenc_t + HD * 2 * FINN;            // 128*256
    unsigned short* wd1t   = w2_t + HD * 2 * HD;                // 384*384
    int* zr = (int*)(wd1t + 384 * 384);
    int* csr_counts   = zr;                                     // N
    int* csr_cursor   = csr_counts + NN;                        // N
    float* group_sums = (float*)(csr_cursor + NN);              // 2G
    int* hist9        = (int*)(group_sums + 2 * GG);            // 9
    int* cursor9      = hist9 + 9;                              // 9
    size_t zero_words = (size_t)NN + NN + 2 * GG + 18;
    int* bsum       = cursor9 + 9;                              // 256
    int* boff       = bsum + 256;                               // 256
    int* boff9      = boff + 256;                               // 10 (+pad 6)
    int* csr_rowptr = boff9 + 16;                               // N+1
    int* dst_rowptr = csr_rowptr + (NN + 1);                    // P+1
    int* var_rowptr = dst_rowptr + (PP + 1);                    // V+1
    int* csr_src    = var_rowptr + (VV + 1);                    // E
    int* pperm      = csr_src + EE;                             // P
    float* logprob  = (float*)(pperm + PP);                     // 2P
    float* within   = logprob + 2 * PP;                         // 2G
    float* total_counts = within + 2 * GG;                      // 1

    hipMemsetAsync(zr, 0, zero_words * 4, stream);
    hipMemsetAsync(d_out, 0, (size_t)out_size * sizeof(float), stream);

    // ---- prep + CSR builds + t-bucket permutation ----
    prep_k<<<(NN * FINN + 255) / 256, 256, 0, stream>>>(x, W_enc_self, W_enc_nei, W2_self,
                                                        W2_nei, Wd1, xb, wenc_t, w2_t, wd1t);
    count_k<<<(EE + 255) / 256, 256, 0, stream>>>(edge_dst, csr_counts, EE);
    blk_sum_k<<<NB, 256, 0, stream>>>(csr_counts, NN, bsum);
    scan_small_k<<<1, 256, 0, stream>>>(bsum, NB, boff);
    rowptr_fill_k<<<NB, 256, 0, stream>>>(csr_counts, boff, NN, csr_rowptr, EE);
    fill_csr_k<<<(EE + 255) / 256, 256, 0, stream>>>(edge_src, edge_dst, csr_rowptr,
                                                     csr_cursor, csr_src, EE);
    lb_rowptr_k<<<(PP + 256) / 256, 256, 0, stream>>>(dst_seg, DD, dst_rowptr, PP);
    lb_rowptr_k<<<(VV + 256) / 256, 256, 0, stream>>>(variant_of_group, GG, var_rowptr, VV);
    hist9_k<<<(PP + 255) / 256, 256, 0, stream>>>(t_idx, hist9);
    scan9_k<<<1, 64, 0, stream>>>(hist9, boff9);
    bucket_perm_k<<<(PP + 255) / 256, 256, 0, stream>>>(t_idx, boff9, cursor9, pperm);

    // ---- 9 fused MP rounds (depth-2 gather), each emitting fp8 shadow ----
    const int NB32 = (NN + 31) / 32;
    for (int r = 0; r <= TT; ++r) {
        const unsigned short* hin = (r == 0) ? xb : ((r & 1) ? rot0 : rot1);
        unsigned short* hout = (r & 1) ? rot1 : rot0;
        unsigned char* houtq = featsq + (size_t)r * NN * HD;
        if (r == 0)
            mpf_k<FINN><<<NB32, 256, 0, stream>>>(hin, csr_rowptr, csr_src, wenc_t, b_enc,
                                                  hout, houtq);
        else
            mpf_k<HD><<<NB32, 256, 0, stream>>>(hin, csr_rowptr, csr_src, w2_t, b2,
                                                hout, houtq);
    }

    // ---- fp8 dst segment-sum + fp8-panel dec9 ----
    dst_sum2q_k<<<(PP + 15) / 16, 256, 0, stream>>>(featsq, t_idx, dst_nodes, dst_rowptr,
                                                    pperm, dstcq);
    dec9_k<<<DEC_GRID, 512, 0, stream>>>(featsq, dstcq, place_idx, src_idx, t_idx,
                                         group_id, pperm, wd1t, bd1, Wd2, bd2,
                                         logprob, group_sums);

    // ---- tail ----
    within_total_k<<<1, 256, 0, stream>>>(group_sums, var_rowptr, counts, within, total_counts);
    final_k<<<(PP + 255) / 256, 256, 0, stream>>>(logprob, within, group_id, variant_of_group,
                                                  counts, total_counts, place_idx, outp);
}

// Round 9
// 954.850 us; speedup vs baseline: 1.1856x; 1.1856x over previous
//
#include <hip/hip_runtime.h>
#include <math.h>

#define NN 50000
#define FINN 64
#define HD 128
#define EE 800000
#define TT 8
#define PP 250000
#define DD 500000
#define GG 20000
#define VV 2000
#define OO 2

#define DEC_GRID 256
#define DEC_TILES ((PP + 63) / 64)

typedef short short8 __attribute__((ext_vector_type(8)));
typedef float f32x4 __attribute__((ext_vector_type(4)));

__device__ __forceinline__ unsigned short f2bf(float f) {
    unsigned int u = __float_as_uint(f);
    u += 0x7fffu + ((u >> 16) & 1u);   // round-to-nearest-even
    return (unsigned short)(u >> 16);
}
__device__ __forceinline__ float bf2f(unsigned short u) {
    return __uint_as_float(((unsigned int)u) << 16);
}

// f32 -> fp8 e4m3fn (via bf16, RTNE, denorm-flush, NaN-guarded clamp)
__device__ __forceinline__ unsigned char q8(float f) {
    unsigned short u = f2bf(f);
    unsigned int e = (u >> 7) & 0xffu;
    unsigned int s = (u >> 8) & 0x80u;
    if (e < 121u) return (unsigned char)s;      // |v| < 2^-6 -> +-0
    unsigned int m = u & 0x7fu;
    unsigned int m3 = m >> 4, rr = m & 0xfu;
    m3 += (rr > 8u) || (rr == 8u && (m3 & 1u));
    unsigned int ee = e - 120u;
    if (m3 == 8u) { m3 = 0u; ++ee; }
    if (ee > 15u || (ee == 15u && m3 == 7u)) { ee = 15u; m3 = 6u; }  // clamp 448, avoid NaN
    return (unsigned char)(s | (ee << 3) | m3);
}
// fp8 byte -> bf16 bits (denormals were flushed at encode) -- dst_sum only
__device__ __forceinline__ unsigned int dq1(unsigned int b) {
    unsigned int t = b & 0x7fu;
    unsigned int r = ((b & 0x80u) << 8) | ((t << 4) + 0x3C00u);
    return t ? r : 0u;
}

struct us8 { unsigned short v[8]; };

__device__ __forceinline__ void gload_lds16(const void* g, void* l) {
    __builtin_amdgcn_global_load_lds((__attribute__((address_space(1))) void*)g,
                                     (__attribute__((address_space(3))) void*)l, 16, 0, 0);
}

// ------------------------------------------------------------------
__global__ void count_k(const int* __restrict__ idx, int* __restrict__ counts, int n) {
    int i = blockIdx.x * blockDim.x + threadIdx.x;
    if (i < n) atomicAdd(&counts[idx[i]], 1);
}

__global__ void blk_sum_k(const int* __restrict__ counts, int n, int* __restrict__ bsum) {
    __shared__ int buf[256];
    int t = threadIdx.x, i = blockIdx.x * 256 + t;
    buf[t] = (i < n) ? counts[i] : 0;
    __syncthreads();
    for (int off = 128; off > 0; off >>= 1) {
        if (t < off) buf[t] += buf[t + off];
        __syncthreads();
    }
    if (t == 0) bsum[blockIdx.x] = buf[0];
}

__global__ void scan_small_k(const int* __restrict__ bsum, int nb, int* __restrict__ boff) {
    __shared__ int buf[256];
    int t = threadIdx.x;
    int v = (t < nb) ? bsum[t] : 0;
    buf[t] = v;
    __syncthreads();
    for (int off = 1; off < 256; off <<= 1) {
        int u = (t >= off) ? buf[t - off] : 0;
        __syncthreads();
        buf[t] += u;
        __syncthreads();
    }
    if (t < nb) boff[t] = buf[t] - v;
}

__global__ void rowptr_fill_k(const int* __restrict__ counts, const int* __restrict__ boff,
                              int n, int* __restrict__ rowptr, int total) {
    __shared__ int buf[256];
    int t = threadIdx.x, i = blockIdx.x * 256 + t;
    int v = (i < n) ? counts[i] : 0;
    buf[t] = v;
    __syncthreads();
    for (int off = 1; off < 256; off <<= 1) {
        int u = (t >= off) ? buf[t - off] : 0;
        __syncthreads();
        buf[t] += u;
        __syncthreads();
    }
    if (i < n) rowptr[i] = boff[blockIdx.x] + buf[t] - v;
    if (i == 0) rowptr[n] = total;
}

__global__ void lb_rowptr_k(const int* __restrict__ arr, int n, int* __restrict__ rowptr, int m) {
    int i = blockIdx.x * blockDim.x + threadIdx.x;
    if (i > m) return;
    int lo = 0, hi = n;
    while (lo < hi) {
        int mid = (lo + hi) >> 1;
        if (arr[mid] < i) lo = mid + 1; else hi = mid;
    }
    rowptr[i] = lo;
}

__global__ void fill_csr_k(const int* __restrict__ esrc, const int* __restrict__ edst,
                           const int* __restrict__ rowptr, int* __restrict__ cursor,
                           int* __restrict__ outi, int n) {
    int e = blockIdx.x * blockDim.x + threadIdx.x;
    if (e < n) {
        int d = edst[e];
        int pos = atomicAdd(&cursor[d], 1);
        outi[rowptr[d] + pos] = esrc[e];
    }
}

// ------------------------------------------------------------------
__global__ void hist9_k(const int* __restrict__ t_idx, int* __restrict__ hist) {
    __shared__ int l[9];
    if (threadIdx.x < 9) l[threadIdx.x] = 0;
    __syncthreads();
    int p = blockIdx.x * 256 + threadIdx.x;
    if (p < PP) atomicAdd(&l[t_idx[p]], 1);
    __syncthreads();
    if (threadIdx.x < 9) atomicAdd(&hist[threadIdx.x], l[threadIdx.x]);
}

__global__ void scan9_k(const int* __restrict__ hist, int* __restrict__ boff9) {
    if (threadIdx.x == 0) {
        int a = 0;
        for (int i = 0; i < 9; ++i) { boff9[i] = a; a += hist[i]; }
        boff9[9] = a;
    }
}

__global__ void bucket_perm_k(const int* __restrict__ t_idx, const int* __restrict__ boff9,
                              int* __restrict__ cursor9, int* __restrict__ pperm) {
    __shared__ int lcnt[9];
    __shared__ int lbase[9];
    int tid = threadIdx.x;
    int p = blockIdx.x * 256 + tid;
    if (tid < 9) lcnt[tid] = 0;
    __syncthreads();
    int t = 0, lr = 0;
    bool ok = p < PP;
    if (ok) {
        t = t_idx[p];
        lr = atomicAdd(&lcnt[t], 1);
    }
    __syncthreads();
    if (tid < 9) lbase[tid] = atomicAdd(&cursor9[tid], lcnt[tid]);
    __syncthreads();
    if (ok) pperm[boff9[t] + lbase[t] + lr] = p;
}

// ------------------------------------------------------------------
__global__ void prep_k(const float* __restrict__ x,
                       const float* __restrict__ Wes, const float* __restrict__ Wen,
                       const float* __restrict__ W2s, const float* __restrict__ W2n,
                       const float* __restrict__ Wd1,
                       unsigned short* __restrict__ xb, unsigned short* __restrict__ wenc_t,
                       unsigned short* __restrict__ w2_t, unsigned short* __restrict__ wd1t,
                       unsigned char* __restrict__ wd1tq) {
    int i = blockIdx.x * 256 + threadIdx.x;
    if (i < NN * FINN) xb[i] = f2bf(x[i]);
    if (i < HD * 2 * FINN) {
        int c = i / (2 * FINN), k = i - c * (2 * FINN);
        wenc_t[i] = f2bf((k < FINN) ? Wes[k * HD + c] : Wen[(k - FINN) * HD + c]);
    }
    if (i < HD * 2 * HD) {
        int c = i / (2 * HD), k = i - c * (2 * HD);
        w2_t[i] = f2bf((k < HD) ? W2s[k * HD + c] : W2n[(k - HD) * HD + c]);
    }
    if (i < 384 * 384) {
        int n = i / 384, k = i - n * 384;
        float v = Wd1[k * 384 + n];
        wd1t[i] = f2bf(v);
        wd1tq[i] = q8(v);
    }
}

// ------------------------------------------------------------------
// mpf: fused mean-agg + MFMA round (depth-2 gather -- R4-proven best).
// Also emits fp8 shadow of the output (houtq, rows of 128 bytes).
template <int KIN>
__launch_bounds__(256)
__global__ void mpf_k(const unsigned short* __restrict__ hin,
                      const int* __restrict__ rowptr, const int* __restrict__ csr_src,
                      const unsigned short* __restrict__ Wt, const float* __restrict__ bias,
                      unsigned short* __restrict__ hout, unsigned char* __restrict__ houtq) {
    constexpr int CPL = KIN / 64;
    __shared__ unsigned short sm[32 * KIN];
    int tid = threadIdx.x;
    int r = tid >> 3;
    int sl = tid & 7;
    int node = blockIdx.x * 32 + r;
    int rx = r & 7;

    if (node < NN) {
        int s = rowptr[node], e = rowptr[node + 1];
        float acc[8 * CPL] = {};
        int i = s, iB = s + 1;
        int srcA = (i < e) ? csr_src[i] : 0;
        int srcB = (iB < e) ? csr_src[iB] : 0;
        while (i < e) {
            bool hB = iB < e;
            us8 vA0, vA1, vB0, vB1;
            vA0 = *(const us8*)&hin[(size_t)srcA * KIN + sl * (8 * CPL)];
            if constexpr (CPL == 2) vA1 = *(const us8*)&hin[(size_t)srcA * KIN + sl * 16 + 8];
            if (hB) {
                vB0 = *(const us8*)&hin[(size_t)srcB * KIN + sl * (8 * CPL)];
                if constexpr (CPL == 2) vB1 = *(const us8*)&hin[(size_t)srcB * KIN + sl * 16 + 8];
            }
            int iN = i + 2, iN2 = i + 3;
            srcA = (iN < e) ? csr_src[iN] : 0;
            srcB = (iN2 < e) ? csr_src[iN2] : 0;
#pragma unroll
            for (int j = 0; j < 8; ++j) acc[j] += bf2f(vA0.v[j]);
            if constexpr (CPL == 2)
#pragma unroll
                for (int j = 0; j < 8; ++j) acc[8 + j] += bf2f(vA1.v[j]);
            if (hB) {
#pragma unroll
                for (int j = 0; j < 8; ++j) acc[j] += bf2f(vB0.v[j]);
                if constexpr (CPL == 2)
#pragma unroll
                    for (int j = 0; j < 8; ++j) acc[8 + j] += bf2f(vB1.v[j]);
            }
            i = iN; iB = iN2;
        }
        float d = fmaxf((float)(e - s), 1.f);
        us8 o0, o1;
#pragma unroll
        for (int j = 0; j < 8; ++j) o0.v[j] = f2bf(acc[j] / d);
        int c0 = sl * CPL;
        *(us8*)&sm[r * KIN + ((c0 ^ rx) * 8)] = o0;
        if constexpr (CPL == 2) {
#pragma unroll
            for (int j = 0; j < 8; ++j) o1.v[j] = f2bf(acc[8 + j] / d);
            *(us8*)&sm[r * KIN + (((c0 + 1) ^ rx) * 8)] = o1;
        }
    }
    __syncthreads();

    // ---- phase B: MFMA ----
    int lane = tid & 63, w = tid >> 6;
    int cc = lane & 15, gq = lane >> 4;
    constexpr int K = 2 * KIN;
    int rloc = (w & 1) * 16 + cc;
    int rowA = blockIdx.x * 32 + rloc;
    bool rowok = rowA < NN;
    const unsigned short* hrow = hin + (size_t)rowA * KIN;
    int ch = (w >> 1) * 64;
    int rlx = rloc & 7;

    f32x4 acc2[4];
#pragma unroll
    for (int t = 0; t < 4; ++t) acc2[t] = (f32x4){0.f, 0.f, 0.f, 0.f};

#pragma unroll
    for (int k0 = 0; k0 < K; k0 += 32) {
        int k = k0 + gq * 8;
        short8 a = {0, 0, 0, 0, 0, 0, 0, 0};
        if (rowok) {
            if (k0 < KIN) a = *(const short8*)(hrow + k);
            else {
                int chunk = (k - KIN) >> 3;
                a = *(const short8*)&sm[rloc * KIN + ((chunk ^ rlx) * 8)];
            }
        }
#pragma unroll
        for (int t = 0; t < 4; ++t) {
            short8 b = *(const short8*)&Wt[(size_t)(ch + t * 16 + cc) * K + k];
            acc2[t] = __builtin_amdgcn_mfma_f32_16x16x32_bf16(a, b, acc2[t], 0, 0, 0);
        }
    }
#pragma unroll
    for (int t = 0; t < 4; ++t) {
        int col = ch + t * 16 + cc;
        float b1 = bias[col];
#pragma unroll
        for (int rj = 0; rj < 4; ++rj) {
            int grow = blockIdx.x * 32 + (w & 1) * 16 + gq * 4 + rj;
            if (grow < NN) {
                float v = fmaxf(acc2[t][rj] + b1, 0.f);
                hout[(size_t)grow * HD + col] = f2bf(v);
                houtq[(size_t)grow * HD + col] = q8(v);
            }
        }
    }
}

// ------------------------------------------------------------------
// dst segment-sum (monolithic, fp8 gather 128B rows, fp8 output).
__launch_bounds__(256)
__global__ void dst_sum2q_k(const unsigned char* __restrict__ featsq,
                            const int* __restrict__ t_idx, const int* __restrict__ dst_nodes,
                            const int* __restrict__ dst_rowptr, const int* __restrict__ pperm,
                            unsigned char* __restrict__ dstcq) {
    int tid = threadIdx.x;
    int grp = tid >> 4;
    int fl = tid & 15;
    int pi = blockIdx.x * 16 + grp;
    if (pi >= PP) return;
    int p = pperm[pi];
    long t = t_idx[p];
    const unsigned char* base = featsq + (size_t)t * NN * HD;
    int s = dst_rowptr[p], e = dst_rowptr[p + 1];
    float acc[8] = {};
    int i = s;
    int n0 = (i < e) ? dst_nodes[i] : 0;
    int n1 = (i + 1 < e) ? dst_nodes[i + 1] : 0;
    while (i < e) {
        bool h1 = (i + 1) < e;
        unsigned long long v0 = *(const unsigned long long*)&base[(size_t)n0 * HD + fl * 8];
        unsigned long long v1 = 0;
        if (h1) v1 = *(const unsigned long long*)&base[(size_t)n1 * HD + fl * 8];
        int i2 = i + 2, i3 = i + 3;
        n0 = (i2 < e) ? dst_nodes[i2] : 0;
        n1 = (i3 < e) ? dst_nodes[i3] : 0;
#pragma unroll
        for (int j = 0; j < 8; ++j)
            acc[j] += bf2f((unsigned short)dq1((unsigned int)(v0 >> (8 * j)) & 0xffu));
        if (h1) {
#pragma unroll
            for (int j = 0; j < 8; ++j)
                acc[j] += bf2f((unsigned short)dq1((unsigned int)(v1 >> (8 * j)) & 0xffu));
        }
        i = i2;
    }
    unsigned long long ov = 0;
#pragma unroll
    for (int j = 0; j < 8; ++j) ov |= (unsigned long long)q8(acc[j]) << (8 * j);
    *(unsigned long long*)&dstcq[(size_t)pi * HD + fl * 8] = ov;
}

// ------------------------------------------------------------------
// dec10: dec9 pipeline with NATIVE fp8 MFMA (no VALU dequant at all).
// A: u64 (8 fp8 bytes) read straight from the staged LDS panel; B: fp8
// Wd1t (wd1tq) in 72 VGPRs. mfma_f32_16x16x32_fp8_fp8 -- same shape/
// C-layout as the bf16 path (C/D layout is dtype-independent on gfx950).
// Counted vmcnt unchanged from dec9 (A=5, S=3, OUT=4): steady 16,
// k<2: 11, nt-2: 13, nt-1: 5.
__global__ void
__attribute__((amdgpu_flat_work_group_size(512, 512), amdgpu_waves_per_eu(2, 2)))
dec10_k(const unsigned char* __restrict__ featsq,
        const unsigned char* __restrict__ dstcq,
        const int* __restrict__ place_idx, const int* __restrict__ src_idx,
        const int* __restrict__ t_idx, const int* __restrict__ group_id,
        const int* __restrict__ pperm,
        const unsigned char* __restrict__ wd1tq,
        const float* __restrict__ bd1, const float* __restrict__ Wd2,
        const float* __restrict__ bd2, float* __restrict__ logprob,
        float* __restrict__ group_sums) {
    __shared__ unsigned char buf[3][192 * 128];      // 3 x 24 KB fp8 A-panels
    __shared__ unsigned int rb[3][192];              // byte offsets from featsq
    __shared__ float lpart[3][8][64][2];

    int tid = threadIdx.x;
    int lane = tid & 63, w = tid >> 6;               // 8 waves
    int cc = lane & 15, gq = lane >> 4;
    int bid = blockIdx.x;

    int row = min(tid, 191);
    int sec = row >> 6, pl = row & 63;
    const int* nptr = (sec == 0) ? place_idx : src_idx;
    unsigned int dstc_off = (unsigned int)(dstcq - featsq);

    int nt = (DEC_TILES - 1 - bid) / DEC_GRID + 1;   // >= 15
    float b20 = bd2[0], b21 = bd2[1];

    // ---- prologue: rb for tiles 0..2, chase regs, hoisted consts ----
    if (tid < 192) {
#pragma unroll
        for (int s3 = 0; s3 < 3; ++s3) {
            int pic = min((bid + s3 * DEC_GRID) * 64 + pl, PP - 1);
            int p = pperm[pic];
            rb[s3][tid] = (sec == 2) ? (dstc_off + (unsigned int)pic * 128u)
                                     : (unsigned int)(((unsigned)t_idx[p] * NN + (unsigned)nptr[p]) * 128u);
        }
    }
    int p3 = pperm[min((bid + 3 * DEC_GRID) * 64 + pl, PP - 1)];
    int tOld = t_idx[p3], nOld = nptr[p3];
    int pCur = pperm[min((bid + 4 * DEC_GRID) * 64 + pl, PP - 1)];
    int opPP = 0, opP = 0, ogP = 0;

    // B-operand: 36 x u64 fp8 (72 VGPRs), cols w*48..w*48+47
    unsigned long long breg[36];
    float b1r[3], w0r[3], w1r[3];
    {
        const unsigned char* bbase = wd1tq + ((long)(w * 48 + cc) * 384 + gq * 8);
#pragma unroll
        for (int kk = 0; kk < 12; ++kk)
#pragma unroll
            for (int t = 0; t < 3; ++t)
                breg[kk * 3 + t] = *(const unsigned long long*)(bbase + (long)t * 16 * 384 + kk * 32);
#pragma unroll
        for (int t = 0; t < 3; ++t) {
            int col = w * 48 + t * 16 + cc;
            b1r[t] = bd1[col];
            w0r[t] = Wd2[col * 2 + 0];
            w1r[t] = Wd2[col * 2 + 1];
        }
    }
    __syncthreads();   // full drain once

    int rsub8 = lane >> 3, chunk8 = lane & 7;

#define STAGE(slot_)                                                                 \
    {                                                                                \
        _Pragma("unroll")                                                            \
        for (int i = 0; i < 3; ++i) {                                                \
            int r = w * 24 + i * 8 + rsub8;                                          \
            const unsigned char* src = featsq + rb[slot_][r] +                       \
                                       ((unsigned)(chunk8 ^ (r & 7)) << 4);          \
            gload_lds16(src, &buf[slot_][(w * 24 + i * 8) * 128]);                   \
        }                                                                            \
    }

#define OUTPUT(tile_, slot_, opv_, ogv_)                                             \
    {                                                                                \
        int pi = (bid + (tile_) * DEC_GRID) * 64 + w * 16 + cc;                      \
        if (pi < PP) {                                                               \
            float l0 = b20, l1 = b21;                                                \
            _Pragma("unroll")                                                        \
            for (int w2 = 0; w2 < 8; ++w2) {                                         \
                l0 += lpart[slot_][w2][w * 16 + cc][0];                              \
                l1 += lpart[slot_][w2][w * 16 + cc][1];                              \
            }                                                                        \
            float mm = fmaxf(l0, l1);                                                \
            float lse = mm + logf(expf(l0 - mm) + expf(l1 - mm));                    \
            float lp0 = l0 - lse, lp1 = l1 - lse;                                    \
            logprob[(opv_)*2 + 0] = lp0;                                             \
            logprob[(opv_)*2 + 1] = lp1;                                             \
            atomicAdd(&group_sums[(ogv_)*2 + 0], lp0);                               \
            atomicAdd(&group_sums[(ogv_)*2 + 1], lp1);                               \
        }                                                                            \
    }

    STAGE(0);
    STAGE(1);

    for (int k = 0; k < nt; ++k) {
        int slot = k % 3;

        // ---- A-phase: 5 idx loads, consumed >=1 iter later ----
        int opN = pperm[min((bid + k * DEC_GRID) * 64 + (w & 3) * 16 + cc, PP - 1)];
        int ogN = group_id[opP];
        int pNew = pperm[min((bid + (k + 5) * DEC_GRID) * 64 + pl, PP - 1)];
        int tNew = t_idx[pCur];
        int nNew = nptr[pCur];
        __builtin_amdgcn_sched_barrier(0);

        // ---- stage tile k+2 (3 VMEM) ----
        if (k + 2 < nt) STAGE((k + 2) % 3);
        __builtin_amdgcn_sched_barrier(0);

        // ---- counted wait: S(k) complete, newer pipeline in flight ----
        if (k + 2 < nt) {
            if (k >= 2) { asm volatile("s_waitcnt vmcnt(16)" ::: "memory"); }
            else        { asm volatile("s_waitcnt vmcnt(11)" ::: "memory"); }
        } else if (k + 1 < nt) {
            asm volatile("s_waitcnt vmcnt(13)" ::: "memory");
        } else {
            asm volatile("s_waitcnt vmcnt(5)" ::: "memory");
        }
        __builtin_amdgcn_s_barrier();
        __builtin_amdgcn_sched_barrier(0);

        // ---- OUTPUT(k-2): stores + atomics only ----
        if (k >= 2 && w < 4 && lane < 16) OUTPUT(k - 2, (k - 2) % 3, opPP, ogP);

        // ---- compute tile k: native fp8 MFMA, zero VMEM, zero dequant ----
        {
            const unsigned char* bufc = &buf[slot][0];
            f32x4 acc[4][3];
#pragma unroll
            for (int s = 0; s < 4; ++s)
#pragma unroll
                for (int t = 0; t < 3; ++t) acc[s][t] = (f32x4){0.f, 0.f, 0.f, 0.f};

#pragma unroll
            for (int kk = 0; kk < 12; ++kk) {
                int seck = kk >> 2;
                int eb = (kk & 3) * 32 + gq * 8;       // byte offset in row
                int c16 = eb >> 4, sub = (eb >> 3) & 1;
                long a_c[4];
#pragma unroll
                for (int s = 0; s < 4; ++s) {
                    int lrow = seck * 64 + s * 16 + cc;
                    a_c[s] = *(const long*)
                        &bufc[lrow * 128 + ((c16 ^ (lrow & 7)) << 4) + sub * 8];
                }
#pragma unroll
                for (int t = 0; t < 3; ++t)
#pragma unroll
                    for (int s = 0; s < 4; ++s)
                        acc[s][t] = __builtin_amdgcn_mfma_f32_16x16x32_fp8_fp8(
                            a_c[s], (long)breg[kk * 3 + t], acc[s][t], 0, 0, 0);
            }

            // ---- epilogue per s ----
#pragma unroll
            for (int s = 0; s < 4; ++s) {
                float p0[4], p1[4];
#pragma unroll
                for (int r = 0; r < 4; ++r) { p0[r] = 0.f; p1[r] = 0.f; }
#pragma unroll
                for (int t = 0; t < 3; ++t) {
#pragma unroll
                    for (int r = 0; r < 4; ++r) {
                        float h = fmaxf(acc[s][t][r] + b1r[t], 0.f);
                        p0[r] += h * w0r[t];
                        p1[r] += h * w1r[t];
                    }
                }
#pragma unroll
                for (int m = 1; m < 16; m <<= 1)
#pragma unroll
                    for (int r = 0; r < 4; ++r) {
                        p0[r] += __shfl_xor(p0[r], m);
                        p1[r] += __shfl_xor(p1[r], m);
                    }
                if (cc == 0) {
#pragma unroll
                    for (int r = 0; r < 4; ++r) {
                        int orow = s * 16 + gq * 4 + r;
                        lpart[slot][w][orow][0] = p0[r];
                        lpart[slot][w][orow][1] = p1[r];
                    }
                }
            }
        }

        // ---- tail: rb for tile k+3 ----
        if (tid < 192) {
            int picw = min((bid + (k + 3) * DEC_GRID) * 64 + pl, PP - 1);
            rb[(k + 3) % 3][tid] = (sec == 2)
                ? (dstc_off + (unsigned int)picw * 128u)
                : (unsigned int)(((unsigned)tOld * NN + (unsigned)nOld) * 128u);
        }
        tOld = tNew; nOld = nNew; pCur = pNew;
        opPP = opP; opP = opN; ogP = ogN;

        asm volatile("s_waitcnt lgkmcnt(0)" ::: "memory");
        __builtin_amdgcn_s_barrier();
        __builtin_amdgcn_sched_barrier(0);
    }

    // ---- post-loop outputs ----
    if (w < 4 && lane < 16) {
        OUTPUT(nt - 2, (nt - 2) % 3, opPP, ogP);
        int ogLast = group_id[opP];
        OUTPUT(nt - 1, (nt - 1) % 3, opP, ogLast);
    }
#undef STAGE
#undef OUTPUT
}

// ------------------------------------------------------------------
__global__ void within_total_k(const float* __restrict__ group_sums,
                               const int* __restrict__ var_rowptr,
                               const float* __restrict__ counts,
                               float* __restrict__ within, float* __restrict__ total) {
    __shared__ float buf[256];
    int tid = threadIdx.x;
    float s = 0.f;
    for (int i = tid; i < VV; i += 256) s += counts[i];
    buf[tid] = s;
    __syncthreads();
    for (int off = 128; off > 0; off >>= 1) {
        if (tid < off) buf[tid] += buf[tid + off];
        __syncthreads();
    }
    if (tid == 0) total[0] = buf[0];
    for (int v = tid; v < VV; v += 256) {
        int gs = var_rowptr[v], ge = var_rowptr[v + 1];
        float r0 = 0.f, r1 = 0.f;
        for (int g = gs; g < ge; ++g) {
            r0 += group_sums[2 * g + 0];
            r1 += group_sums[2 * g + 1];
            within[2 * g + 0] = r0;
            within[2 * g + 1] = r1;
        }
    }
}

__global__ void final_k(const float* __restrict__ logprob, const float* __restrict__ within,
                        const int* __restrict__ group_id, const int* __restrict__ vog,
                        const float* __restrict__ counts, const float* __restrict__ total,
                        const int* __restrict__ place_idx, float* __restrict__ outp) {
    int p = blockIdx.x * blockDim.x + threadIdx.x;
    if (p >= PP) return;
    int g = group_id[p];
    int v = vog[g];
    float lc = logf(counts[v]) - logf(total[0]);
    int node = place_idx[p];
    atomicAdd(&outp[node * 2 + 0], logprob[p * 2 + 0] + within[g * 2 + 0] + lc);
    atomicAdd(&outp[node * 2 + 1], logprob[p * 2 + 1] + within[g * 2 + 1] + lc);
}

// ------------------------------------------------------------------
extern "C" void kernel_launch(void* const* d_in, const int* in_sizes, int n_in,
                              void* d_out, int out_size, void* d_ws, size_t ws_size,
                              hipStream_t stream) {
    const float* x          = (const float*)d_in[0];
    const float* W_enc_self = (const float*)d_in[1];
    const float* W_enc_nei  = (const float*)d_in[2];
    const float* b_enc      = (const float*)d_in[3];
    const float* W2_self    = (const float*)d_in[4];
    const float* W2_nei     = (const float*)d_in[5];
    const float* b2         = (const float*)d_in[6];
    const float* Wd1        = (const float*)d_in[7];
    const float* bd1        = (const float*)d_in[8];
    const float* Wd2        = (const float*)d_in[9];
    const float* bd2        = (const float*)d_in[10];
    const float* counts     = (const float*)d_in[11];
    const int* edge_src     = (const int*)d_in[12];
    const int* edge_dst     = (const int*)d_in[13];
    const int* place_idx    = (const int*)d_in[14];
    const int* src_idx      = (const int*)d_in[15];
    const int* t_idx        = (const int*)d_in[16];
    const int* dst_nodes    = (const int*)d_in[17];
    const int* dst_seg      = (const int*)d_in[18];
    const int* group_id     = (const int*)d_in[19];
    const int* variant_of_group = (const int*)d_in[20];
    float* outp = (float*)d_out;

    const int NB = (NN + 255) / 256;

    // ---- workspace layout (rotating bf16 feats + fp8 shadows) ----
    unsigned short* rot0 = (unsigned short*)d_ws;               // N*H bf16
    unsigned short* rot1 = rot0 + (size_t)NN * HD;              // N*H bf16
    unsigned short* xb   = rot1 + (size_t)NN * HD;              // N*FIN bf16
    unsigned char* featsq = (unsigned char*)(xb + (size_t)NN * FINN);  // 9*N*128 fp8
    unsigned char* dstcq  = featsq + (size_t)(TT + 1) * NN * HD;       // P*128 fp8
    unsigned short* wenc_t = (unsigned short*)(dstcq + (size_t)PP * HD); // 128*128
    unsigned short* w2_t   = wenc_t + HD * 2 * FINN;            // 128*256
    unsigned short* wd1t   = w2_t + HD * 2 * HD;                // 384*384 bf16
    unsigned char* wd1tq   = (unsigned char*)(wd1t + 384 * 384);  // 384*384 fp8
    int* zr = (int*)(wd1tq + 384 * 384);
    int* csr_counts   = zr;                                     // N
    int* csr_cursor   = csr_counts + NN;                        // N
    float* group_sums = (float*)(csr_cursor + NN);              // 2G
    int* hist9        = (int*)(group_sums + 2 * GG);            // 9
    int* cursor9      = hist9 + 9;                              // 9
    size_t zero_words = (size_t)NN + NN + 2 * GG + 18;
    int* bsum       = cursor9 + 9;                              // 256
    int* boff       = bsum + 256;                               // 256
    int* boff9      = boff + 256;                               // 10 (+pad 6)
    int* csr_rowptr = boff9 + 16;                               // N+1
    int* dst_rowptr = csr_rowptr + (NN + 1);                    // P+1
    int* var_rowptr = dst_rowptr + (PP + 1);                    // V+1
    int* csr_src    = var_rowptr + (VV + 1);                    // E
    int* pperm      = csr_src + EE;                             // P
    float* logprob  = (float*)(pperm + PP);                     // 2P
    float* within   = logprob + 2 * PP;                         // 2G
    float* total_counts = within + 2 * GG;                      // 1

    hipMemsetAsync(zr, 0, zero_words * 4, stream);
    hipMemsetAsync(d_out, 0, (size_t)out_size * sizeof(float), stream);

    // ---- prep + CSR builds + t-bucket permutation ----
    prep_k<<<(NN * FINN + 255) / 256, 256, 0, stream>>>(x, W_enc_self, W_enc_nei, W2_self,
                                                        W2_nei, Wd1, xb, wenc_t, w2_t,
                                                        wd1t, wd1tq);
    count_k<<<(EE + 255) / 256, 256, 0, stream>>>(edge_dst, csr_counts, EE);
    blk_sum_k<<<NB, 256, 0, stream>>>(csr_counts, NN, bsum);
    scan_small_k<<<1, 256, 0, stream>>>(bsum, NB, boff);
    rowptr_fill_k<<<NB, 256, 0, stream>>>(csr_counts, boff, NN, csr_rowptr, EE);
    fill_csr_k<<<(EE + 255) / 256, 256, 0, stream>>>(edge_src, edge_dst, csr_rowptr,
                                                     csr_cursor, csr_src, EE);
    lb_rowptr_k<<<(PP + 256) / 256, 256, 0, stream>>>(dst_seg, DD, dst_rowptr, PP);
    lb_rowptr_k<<<(VV + 256) / 256, 256, 0, stream>>>(variant_of_group, GG, var_rowptr, VV);
    hist9_k<<<(PP + 255) / 256, 256, 0, stream>>>(t_idx, hist9);
    scan9_k<<<1, 64, 0, stream>>>(hist9, boff9);
    bucket_perm_k<<<(PP + 255) / 256, 256, 0, stream>>>(t_idx, boff9, cursor9, pperm);

    // ---- 9 fused MP rounds (depth-2 gather), each emitting fp8 shadow ----
    const int NB32 = (NN + 31) / 32;
    for (int r = 0; r <= TT; ++r) {
        const unsigned short* hin = (r == 0) ? xb : ((r & 1) ? rot0 : rot1);
        unsigned short* hout = (r & 1) ? rot1 : rot0;
        unsigned char* houtq = featsq + (size_t)r * NN * HD;
        if (r == 0)
            mpf_k<FINN><<<NB32, 256, 0, stream>>>(hin, csr_rowptr, csr_src, wenc_t, b_enc,
                                                  hout, houtq);
        else
            mpf_k<HD><<<NB32, 256, 0, stream>>>(hin, csr_rowptr, csr_src, w2_t, b2,
                                                hout, houtq);
    }

    // ---- fp8 dst segment-sum + native-fp8-MFMA dec10 ----
    dst_sum2q_k<<<(PP + 15) / 16, 256, 0, stream>>>(featsq, t_idx, dst_nodes, dst_rowptr,
                                                    pperm, dstcq);
    dec10_k<<<DEC_GRID, 512, 0, stream>>>(featsq, dstcq, place_idx, src_idx, t_idx,
                                          group_id, pperm, wd1tq, bd1, Wd2, bd2,
                                          logprob, group_sums);

    // ---- tail ----
    within_total_k<<<1, 256, 0, stream>>>(group_sums, var_rowptr, counts, within, total_counts);
    final_k<<<(PP + 255) / 256, 256, 0, stream>>>(logprob, within, group_id, variant_of_group,
                                                  counts, total_counts, place_idx, outp);
}

// Round 10
// 910.213 us; speedup vs baseline: 1.2437x; 1.0490x over previous
//
#include <hip/hip_runtime.h>
#include <math.h>

#define NN 50000
#define FINN 64
#define HD 128
#define EE 800000
#define TT 8
#define PP 250000
#define DD 500000
#define GG 20000
#define VV 2000
#define OO 2

#define DEC_GRID 256
#define DEC_TILES ((PP + 63) / 64)

typedef short short8 __attribute__((ext_vector_type(8)));
typedef float f32x4 __attribute__((ext_vector_type(4)));
typedef unsigned int uint2v __attribute__((ext_vector_type(2)));
typedef unsigned int uint4v __attribute__((ext_vector_type(4)));

__device__ __forceinline__ unsigned short f2bf(float f) {
    unsigned int u = __float_as_uint(f);
    u += 0x7fffu + ((u >> 16) & 1u);   // round-to-nearest-even
    return (unsigned short)(u >> 16);
}
__device__ __forceinline__ float bf2f(unsigned short u) {
    return __uint_as_float(((unsigned int)u) << 16);
}

// f32 -> fp8 e4m3fn (via bf16, RTNE, denorm-flush, NaN-guarded clamp)
__device__ __forceinline__ unsigned char q8(float f) {
    unsigned short u = f2bf(f);
    unsigned int e = (u >> 7) & 0xffu;
    unsigned int s = (u >> 8) & 0x80u;
    if (e < 121u) return (unsigned char)s;      // |v| < 2^-6 -> +-0
    unsigned int m = u & 0x7fu;
    unsigned int m3 = m >> 4, rr = m & 0xfu;
    m3 += (rr > 8u) || (rr == 8u && (m3 & 1u));
    unsigned int ee = e - 120u;
    if (m3 == 8u) { m3 = 0u; ++ee; }
    if (ee > 15u || (ee == 15u && m3 == 7u)) { ee = 15u; m3 = 6u; }  // clamp 448, avoid NaN
    return (unsigned char)(s | (ee << 3) | m3);
}
// fp8 byte -> bf16 bits (denormals were flushed at encode) -- fallback only
__device__ __forceinline__ unsigned int dq1(unsigned int b) {
    unsigned int t = b & 0x7fu;
    unsigned int r = ((b & 0x80u) << 8) | ((t << 4) + 0x3C00u);
    return t ? r : 0u;
}

// accumulate 4 fp8 elems of a u32 into acc[0..3] -- HW convert when available
#if __has_builtin(__builtin_amdgcn_cvt_pk_f32_fp8)
typedef float float2v __attribute__((ext_vector_type(2)));
__device__ __forceinline__ void acc_u32(float* acc, unsigned int w) {
    float2v lo = __builtin_amdgcn_cvt_pk_f32_fp8(w, false);
    float2v hi = __builtin_amdgcn_cvt_pk_f32_fp8(w, true);
    acc[0] += lo[0]; acc[1] += lo[1]; acc[2] += hi[0]; acc[3] += hi[1];
}
#else
__device__ __forceinline__ void acc_u32(float* acc, unsigned int w) {
    acc[0] += bf2f((unsigned short)dq1(w & 0xffu));
    acc[1] += bf2f((unsigned short)dq1((w >> 8) & 0xffu));
    acc[2] += bf2f((unsigned short)dq1((w >> 16) & 0xffu));
    acc[3] += bf2f((unsigned short)dq1((w >> 24) & 0xffu));
}
#endif

struct us8 { unsigned short v[8]; };

__device__ __forceinline__ void gload_lds16(const void* g, void* l) {
    __builtin_amdgcn_global_load_lds((__attribute__((address_space(1))) void*)g,
                                     (__attribute__((address_space(3))) void*)l, 16, 0, 0);
}

// ------------------------------------------------------------------
__global__ void count_k(const int* __restrict__ idx, int* __restrict__ counts, int n) {
    int i = blockIdx.x * blockDim.x + threadIdx.x;
    if (i < n) atomicAdd(&counts[idx[i]], 1);
}

__global__ void blk_sum_k(const int* __restrict__ counts, int n, int* __restrict__ bsum) {
    __shared__ int buf[256];
    int t = threadIdx.x, i = blockIdx.x * 256 + t;
    buf[t] = (i < n) ? counts[i] : 0;
    __syncthreads();
    for (int off = 128; off > 0; off >>= 1) {
        if (t < off) buf[t] += buf[t + off];
        __syncthreads();
    }
    if (t == 0) bsum[blockIdx.x] = buf[0];
}

__global__ void scan_small_k(const int* __restrict__ bsum, int nb, int* __restrict__ boff) {
    __shared__ int buf[256];
    int t = threadIdx.x;
    int v = (t < nb) ? bsum[t] : 0;
    buf[t] = v;
    __syncthreads();
    for (int off = 1; off < 256; off <<= 1) {
        int u = (t >= off) ? buf[t - off] : 0;
        __syncthreads();
        buf[t] += u;
        __syncthreads();
    }
    if (t < nb) boff[t] = buf[t] - v;
}

__global__ void rowptr_fill_k(const int* __restrict__ counts, const int* __restrict__ boff,
                              int n, int* __restrict__ rowptr, int total) {
    __shared__ int buf[256];
    int t = threadIdx.x, i = blockIdx.x * 256 + t;
    int v = (i < n) ? counts[i] : 0;
    buf[t] = v;
    __syncthreads();
    for (int off = 1; off < 256; off <<= 1) {
        int u = (t >= off) ? buf[t - off] : 0;
        __syncthreads();
        buf[t] += u;
        __syncthreads();
    }
    if (i < n) rowptr[i] = boff[blockIdx.x] + buf[t] - v;
    if (i == 0) rowptr[n] = total;
}

__global__ void lb_rowptr_k(const int* __restrict__ arr, int n, int* __restrict__ rowptr, int m) {
    int i = blockIdx.x * blockDim.x + threadIdx.x;
    if (i > m) return;
    int lo = 0, hi = n;
    while (lo < hi) {
        int mid = (lo + hi) >> 1;
        if (arr[mid] < i) lo = mid + 1; else hi = mid;
    }
    rowptr[i] = lo;
}

__global__ void fill_csr_k(const int* __restrict__ esrc, const int* __restrict__ edst,
                           const int* __restrict__ rowptr, int* __restrict__ cursor,
                           int* __restrict__ outi, int n) {
    int e = blockIdx.x * blockDim.x + threadIdx.x;
    if (e < n) {
        int d = edst[e];
        int pos = atomicAdd(&cursor[d], 1);
        outi[rowptr[d] + pos] = esrc[e];
    }
}

// ------------------------------------------------------------------
__global__ void hist9_k(const int* __restrict__ t_idx, int* __restrict__ hist) {
    __shared__ int l[9];
    if (threadIdx.x < 9) l[threadIdx.x] = 0;
    __syncthreads();
    int p = blockIdx.x * 256 + threadIdx.x;
    if (p < PP) atomicAdd(&l[t_idx[p]], 1);
    __syncthreads();
    if (threadIdx.x < 9) atomicAdd(&hist[threadIdx.x], l[threadIdx.x]);
}

__global__ void scan9_k(const int* __restrict__ hist, int* __restrict__ boff9) {
    if (threadIdx.x == 0) {
        int a = 0;
        for (int i = 0; i < 9; ++i) { boff9[i] = a; a += hist[i]; }
        boff9[9] = a;
    }
}

__global__ void bucket_perm_k(const int* __restrict__ t_idx, const int* __restrict__ boff9,
                              int* __restrict__ cursor9, int* __restrict__ pperm) {
    __shared__ int lcnt[9];
    __shared__ int lbase[9];
    int tid = threadIdx.x;
    int p = blockIdx.x * 256 + tid;
    if (tid < 9) lcnt[tid] = 0;
    __syncthreads();
    int t = 0, lr = 0;
    bool ok = p < PP;
    if (ok) {
        t = t_idx[p];
        lr = atomicAdd(&lcnt[t], 1);
    }
    __syncthreads();
    if (tid < 9) lbase[tid] = atomicAdd(&cursor9[tid], lcnt[tid]);
    __syncthreads();
    if (ok) pperm[boff9[t] + lbase[t] + lr] = p;
}

// ------------------------------------------------------------------
__global__ void prep_k(const float* __restrict__ x,
                       const float* __restrict__ Wes, const float* __restrict__ Wen,
                       const float* __restrict__ W2s, const float* __restrict__ W2n,
                       const float* __restrict__ Wd1,
                       unsigned short* __restrict__ xb, unsigned char* __restrict__ xbq,
                       unsigned short* __restrict__ wenc_t,
                       unsigned short* __restrict__ w2_t, unsigned short* __restrict__ wd1t,
                       unsigned char* __restrict__ wd1tq) {
    int i = blockIdx.x * 256 + threadIdx.x;
    if (i < NN * FINN) {
        float v = x[i];
        xb[i] = f2bf(v);
        xbq[i] = q8(v);
    }
    if (i < HD * 2 * FINN) {
        int c = i / (2 * FINN), k = i - c * (2 * FINN);
        wenc_t[i] = f2bf((k < FINN) ? Wes[k * HD + c] : Wen[(k - FINN) * HD + c]);
    }
    if (i < HD * 2 * HD) {
        int c = i / (2 * HD), k = i - c * (2 * HD);
        w2_t[i] = f2bf((k < HD) ? W2s[k * HD + c] : W2n[(k - HD) * HD + c]);
    }
    if (i < 384 * 384) {
        int n = i / 384, k = i - n * 384;
        float v = Wd1[k * 384 + n];
        wd1t[i] = f2bf(v);
        wd1tq[i] = q8(v);
    }
}

// ------------------------------------------------------------------
// mpf2: fused mean-agg + MFMA round. Phase A gathers the FP8 shadow
// (half the bytes/lines of bf16) and converts with the HW
// v_cvt_pk_f32_fp8 (2 elems/op -- cheaper than bf16 unpack). Self path
// in phase B stays bf16. Emits both bf16 hout and fp8 houtq.
template <int KIN>
__launch_bounds__(256)
__global__ void mpf2_k(const unsigned short* __restrict__ hin,
                       const unsigned char* __restrict__ hinq,
                       const int* __restrict__ rowptr, const int* __restrict__ csr_src,
                       const unsigned short* __restrict__ Wt, const float* __restrict__ bias,
                       unsigned short* __restrict__ hout, unsigned char* __restrict__ houtq) {
    constexpr int CPL = KIN / 64;          // 2 for 128, 1 for 64
    __shared__ unsigned short sm[32 * KIN];
    int tid = threadIdx.x;
    int r = tid >> 3;
    int sl = tid & 7;
    int node = blockIdx.x * 32 + r;
    int rx = r & 7;

    if (node < NN) {
        int s = rowptr[node], e = rowptr[node + 1];
        float acc[8 * CPL] = {};
        int i = s, iB = s + 1;
        int srcA = (i < e) ? csr_src[i] : 0;
        int srcB = (iB < e) ? csr_src[iB] : 0;
        while (i < e) {
            bool hB = iB < e;
            uint4v vA, vB;
            uint2v wA, wB;
            if constexpr (CPL == 2) {
                vA = *(const uint4v*)&hinq[(size_t)srcA * KIN + sl * 16];
                if (hB) vB = *(const uint4v*)&hinq[(size_t)srcB * KIN + sl * 16];
            } else {
                wA = *(const uint2v*)&hinq[(size_t)srcA * KIN + sl * 8];
                if (hB) wB = *(const uint2v*)&hinq[(size_t)srcB * KIN + sl * 8];
            }
            int iN = i + 2, iN2 = i + 3;
            srcA = (iN < e) ? csr_src[iN] : 0;
            srcB = (iN2 < e) ? csr_src[iN2] : 0;
            if constexpr (CPL == 2) {
                acc_u32(acc + 0, vA[0]); acc_u32(acc + 4, vA[1]);
                acc_u32(acc + 8, vA[2]); acc_u32(acc + 12, vA[3]);
                if (hB) {
                    acc_u32(acc + 0, vB[0]); acc_u32(acc + 4, vB[1]);
                    acc_u32(acc + 8, vB[2]); acc_u32(acc + 12, vB[3]);
                }
            } else {
                acc_u32(acc + 0, wA[0]); acc_u32(acc + 4, wA[1]);
                if (hB) { acc_u32(acc + 0, wB[0]); acc_u32(acc + 4, wB[1]); }
            }
            i = iN; iB = iN2;
        }
        float d = fmaxf((float)(e - s), 1.f);
        us8 o0, o1;
#pragma unroll
        for (int j = 0; j < 8; ++j) o0.v[j] = f2bf(acc[j] / d);
        int c0 = sl * CPL;
        *(us8*)&sm[r * KIN + ((c0 ^ rx) * 8)] = o0;
        if constexpr (CPL == 2) {
#pragma unroll
            for (int j = 0; j < 8; ++j) o1.v[j] = f2bf(acc[8 + j] / d);
            *(us8*)&sm[r * KIN + (((c0 + 1) ^ rx) * 8)] = o1;
        }
    }
    __syncthreads();

    // ---- phase B: MFMA (bf16 self + bf16 LDS agg) ----
    int lane = tid & 63, w = tid >> 6;
    int cc = lane & 15, gq = lane >> 4;
    constexpr int K = 2 * KIN;
    int rloc = (w & 1) * 16 + cc;
    int rowA = blockIdx.x * 32 + rloc;
    bool rowok = rowA < NN;
    const unsigned short* hrow = hin + (size_t)rowA * KIN;
    int ch = (w >> 1) * 64;
    int rlx = rloc & 7;

    f32x4 acc2[4];
#pragma unroll
    for (int t = 0; t < 4; ++t) acc2[t] = (f32x4){0.f, 0.f, 0.f, 0.f};

#pragma unroll
    for (int k0 = 0; k0 < K; k0 += 32) {
        int k = k0 + gq * 8;
        short8 a = {0, 0, 0, 0, 0, 0, 0, 0};
        if (rowok) {
            if (k0 < KIN) a = *(const short8*)(hrow + k);
            else {
                int chunk = (k - KIN) >> 3;
                a = *(const short8*)&sm[rloc * KIN + ((chunk ^ rlx) * 8)];
            }
        }
#pragma unroll
        for (int t = 0; t < 4; ++t) {
            short8 b = *(const short8*)&Wt[(size_t)(ch + t * 16 + cc) * K + k];
            acc2[t] = __builtin_amdgcn_mfma_f32_16x16x32_bf16(a, b, acc2[t], 0, 0, 0);
        }
    }
#pragma unroll
    for (int t = 0; t < 4; ++t) {
        int col = ch + t * 16 + cc;
        float b1 = bias[col];
#pragma unroll
        for (int rj = 0; rj < 4; ++rj) {
            int grow = blockIdx.x * 32 + (w & 1) * 16 + gq * 4 + rj;
            if (grow < NN) {
                float v = fmaxf(acc2[t][rj] + b1, 0.f);
                hout[(size_t)grow * HD + col] = f2bf(v);
                houtq[(size_t)grow * HD + col] = q8(v);
            }
        }
    }
}

// ------------------------------------------------------------------
// dst segment-sum (monolithic, fp8 gather 128B rows, fp8 output).
__launch_bounds__(256)
__global__ void dst_sum2q_k(const unsigned char* __restrict__ featsq,
                            const int* __restrict__ t_idx, const int* __restrict__ dst_nodes,
                            const int* __restrict__ dst_rowptr, const int* __restrict__ pperm,
                            unsigned char* __restrict__ dstcq) {
    int tid = threadIdx.x;
    int grp = tid >> 4;
    int fl = tid & 15;
    int pi = blockIdx.x * 16 + grp;
    if (pi >= PP) return;
    int p = pperm[pi];
    long t = t_idx[p];
    const unsigned char* base = featsq + (size_t)t * NN * HD;
    int s = dst_rowptr[p], e = dst_rowptr[p + 1];
    float acc[8] = {};
    int i = s;
    int n0 = (i < e) ? dst_nodes[i] : 0;
    int n1 = (i + 1 < e) ? dst_nodes[i + 1] : 0;
    while (i < e) {
        bool h1 = (i + 1) < e;
        uint2v v0 = *(const uint2v*)&base[(size_t)n0 * HD + fl * 8];
        uint2v v1;
        if (h1) v1 = *(const uint2v*)&base[(size_t)n1 * HD + fl * 8];
        int i2 = i + 2, i3 = i + 3;
        n0 = (i2 < e) ? dst_nodes[i2] : 0;
        n1 = (i3 < e) ? dst_nodes[i3] : 0;
        acc_u32(acc + 0, v0[0]); acc_u32(acc + 4, v0[1]);
        if (h1) { acc_u32(acc + 0, v1[0]); acc_u32(acc + 4, v1[1]); }
        i = i2;
    }
    unsigned long long ov = 0;
#pragma unroll
    for (int j = 0; j < 8; ++j) ov |= (unsigned long long)q8(acc[j]) << (8 * j);
    *(unsigned long long*)&dstcq[(size_t)pi * HD + fl * 8] = ov;
}

// ------------------------------------------------------------------
// dec11: dec10 with prefetch depth 3 (4 LDS panel slots) -- probes
// whether the remaining 18K cyc/tile responds to more outstanding
// stages. Native fp8 MFMA, breg-resident fp8 B, counted vmcnt ladder
// re-derived op-by-op for depth 3 (A=5, S=3, OUT=4 per wave/iter):
// ramp {14,19,24}, steady 24, drain {21,18,15}.
__global__ void
__attribute__((amdgpu_flat_work_group_size(512, 512), amdgpu_waves_per_eu(2, 2)))
dec11_k(const unsigned char* __restrict__ featsq,
        const unsigned char* __restrict__ dstcq,
        const int* __restrict__ place_idx, const int* __restrict__ src_idx,
        const int* __restrict__ t_idx, const int* __restrict__ group_id,
        const int* __restrict__ pperm,
        const unsigned char* __restrict__ wd1tq,
        const float* __restrict__ bd1, const float* __restrict__ Wd2,
        const float* __restrict__ bd2, float* __restrict__ logprob,
        float* __restrict__ group_sums) {
    __shared__ unsigned char buf[4][192 * 128];      // 4 x 24 KB fp8 A-panels
    __shared__ unsigned int rb[4][192];              // byte offsets from featsq
    __shared__ float lpart[3][8][64][2];

    int tid = threadIdx.x;
    int lane = tid & 63, w = tid >> 6;               // 8 waves
    int cc = lane & 15, gq = lane >> 4;
    int bid = blockIdx.x;

    int row = min(tid, 191);
    int sec = row >> 6, pl = row & 63;
    const int* nptr = (sec == 0) ? place_idx : src_idx;
    unsigned int dstc_off = (unsigned int)(dstcq - featsq);

    int nt = (DEC_TILES - 1 - bid) / DEC_GRID + 1;   // >= 15
    float b20 = bd2[0], b21 = bd2[1];

    // ---- prologue: rb for tiles 0..3, chase regs for 4/5, consts ----
    if (tid < 192) {
#pragma unroll
        for (int s4 = 0; s4 < 4; ++s4) {
            int pic = min((bid + s4 * DEC_GRID) * 64 + pl, PP - 1);
            int p = pperm[pic];
            rb[s4][tid] = (sec == 2) ? (dstc_off + (unsigned int)pic * 128u)
                                     : (unsigned int)(((unsigned)t_idx[p] * NN + (unsigned)nptr[p]) * 128u);
        }
    }
    int p4 = pperm[min((bid + 4 * DEC_GRID) * 64 + pl, PP - 1)];
    int tOld = t_idx[p4], nOld = nptr[p4];
    int pCur = pperm[min((bid + 5 * DEC_GRID) * 64 + pl, PP - 1)];
    int opPP = 0, opP = 0, ogP = 0;

    // B-operand: 36 x u64 fp8 (72 VGPRs), cols w*48..w*48+47
    unsigned long long breg[36];
    float b1r[3], w0r[3], w1r[3];
    {
        const unsigned char* bbase = wd1tq + ((long)(w * 48 + cc) * 384 + gq * 8);
#pragma unroll
        for (int kk = 0; kk < 12; ++kk)
#pragma unroll
            for (int t = 0; t < 3; ++t)
                breg[kk * 3 + t] = *(const unsigned long long*)(bbase + (long)t * 16 * 384 + kk * 32);
#pragma unroll
        for (int t = 0; t < 3; ++t) {
            int col = w * 48 + t * 16 + cc;
            b1r[t] = bd1[col];
            w0r[t] = Wd2[col * 2 + 0];
            w1r[t] = Wd2[col * 2 + 1];
        }
    }
    __syncthreads();   // full drain once

    int rsub8 = lane >> 3, chunk8 = lane & 7;

#define STAGE(slot_)                                                                 \
    {                                                                                \
        _Pragma("unroll")                                                            \
        for (int i = 0; i < 3; ++i) {                                                \
            int r = w * 24 + i * 8 + rsub8;                                          \
            const unsigned char* src = featsq + rb[slot_][r] +                       \
                                       ((unsigned)(chunk8 ^ (r & 7)) << 4);          \
            gload_lds16(src, &buf[slot_][(w * 24 + i * 8) * 128]);                   \
        }                                                                            \
    }

#define OUTPUT(tile_, slot_, opv_, ogv_)                                             \
    {                                                                                \
        int pi = (bid + (tile_) * DEC_GRID) * 64 + w * 16 + cc;                      \
        if (pi < PP) {                                                               \
            float l0 = b20, l1 = b21;                                                \
            _Pragma("unroll")                                                        \
            for (int w2 = 0; w2 < 8; ++w2) {                                         \
                l0 += lpart[slot_][w2][w * 16 + cc][0];                              \
                l1 += lpart[slot_][w2][w * 16 + cc][1];                              \
            }                                                                        \
            float mm = fmaxf(l0, l1);                                                \
            float lse = mm + logf(expf(l0 - mm) + expf(l1 - mm));                    \
            float lp0 = l0 - lse, lp1 = l1 - lse;                                    \
            logprob[(opv_)*2 + 0] = lp0;                                             \
            logprob[(opv_)*2 + 1] = lp1;                                             \
            atomicAdd(&group_sums[(ogv_)*2 + 0], lp0);                               \
            atomicAdd(&group_sums[(ogv_)*2 + 1], lp1);                               \
        }                                                                            \
    }

    STAGE(0);
    STAGE(1);
    STAGE(2);

    for (int k = 0; k < nt; ++k) {
        int slot = k & 3;

        // ---- A-phase: 5 idx loads, consumed >=1 iter later ----
        int opN = pperm[min((bid + k * DEC_GRID) * 64 + (w & 3) * 16 + cc, PP - 1)];
        int ogN = group_id[opP];
        int pNew = pperm[min((bid + (k + 6) * DEC_GRID) * 64 + pl, PP - 1)];
        int tNew = t_idx[pCur];
        int nNew = nptr[pCur];
        __builtin_amdgcn_sched_barrier(0);

        // ---- stage tile k+3 (3 VMEM) ----
        if (k + 3 < nt) STAGE((k + 3) & 3);
        __builtin_amdgcn_sched_barrier(0);

        // ---- counted wait: S(k) complete, newer pipeline in flight ----
        if (k + 3 < nt) {
            if (k >= 2)      { asm volatile("s_waitcnt vmcnt(24)" ::: "memory"); }
            else if (k == 1) { asm volatile("s_waitcnt vmcnt(19)" ::: "memory"); }
            else             { asm volatile("s_waitcnt vmcnt(14)" ::: "memory"); }
        } else if (k + 2 < nt) {
            asm volatile("s_waitcnt vmcnt(21)" ::: "memory");
        } else if (k + 1 < nt) {
            asm volatile("s_waitcnt vmcnt(18)" ::: "memory");
        } else {
            asm volatile("s_waitcnt vmcnt(15)" ::: "memory");
        }
        __builtin_amdgcn_s_barrier();
        __builtin_amdgcn_sched_barrier(0);

        // ---- OUTPUT(k-2): stores + atomics only ----
        if (k >= 2 && w < 4 && lane < 16) OUTPUT(k - 2, (k - 2) % 3, opPP, ogP);

        // ---- compute tile k: native fp8 MFMA, zero VMEM ----
        {
            const unsigned char* bufc = &buf[slot][0];
            f32x4 acc[4][3];
#pragma unroll
            for (int s = 0; s < 4; ++s)
#pragma unroll
                for (int t = 0; t < 3; ++t) acc[s][t] = (f32x4){0.f, 0.f, 0.f, 0.f};

#pragma unroll
            for (int kk = 0; kk < 12; ++kk) {
                int seck = kk >> 2;
                int eb = (kk & 3) * 32 + gq * 8;       // byte offset in row
                int c16 = eb >> 4, sub = (eb >> 3) & 1;
                long a_c[4];
#pragma unroll
                for (int s = 0; s < 4; ++s) {
                    int lrow = seck * 64 + s * 16 + cc;
                    a_c[s] = *(const long*)
                        &bufc[lrow * 128 + ((c16 ^ (lrow & 7)) << 4) + sub * 8];
                }
#pragma unroll
                for (int t = 0; t < 3; ++t)
#pragma unroll
                    for (int s = 0; s < 4; ++s)
                        acc[s][t] = __builtin_amdgcn_mfma_f32_16x16x32_fp8_fp8(
                            a_c[s], (long)breg[kk * 3 + t], acc[s][t], 0, 0, 0);
            }

            // ---- epilogue per s ----
#pragma unroll
            for (int s = 0; s < 4; ++s) {
                float p0[4], p1[4];
#pragma unroll
                for (int r = 0; r < 4; ++r) { p0[r] = 0.f; p1[r] = 0.f; }
#pragma unroll
                for (int t = 0; t < 3; ++t) {
#pragma unroll
                    for (int r = 0; r < 4; ++r) {
                        float h = fmaxf(acc[s][t][r] + b1r[t], 0.f);
                        p0[r] += h * w0r[t];
                        p1[r] += h * w1r[t];
                    }
                }
#pragma unroll
                for (int m = 1; m < 16; m <<= 1)
#pragma unroll
                    for (int r = 0; r < 4; ++r) {
                        p0[r] += __shfl_xor(p0[r], m);
                        p1[r] += __shfl_xor(p1[r], m);
                    }
                if (cc == 0) {
#pragma unroll
                    for (int r = 0; r < 4; ++r) {
                        int orow = s * 16 + gq * 4 + r;
                        lpart[k % 3][w][orow][0] = p0[r];
                        lpart[k % 3][w][orow][1] = p1[r];
                    }
                }
            }
        }

        // ---- tail: rb for tile k+4 into slot k&3 (freed by S(k)) ----
        if (tid < 192) {
            int picw = min((bid + (k + 4) * DEC_GRID) * 64 + pl, PP - 1);
            rb[k & 3][tid] = (sec == 2)
                ? (dstc_off + (unsigned int)picw * 128u)
                : (unsigned int)(((unsigned)tOld * NN + (unsigned)nOld) * 128u);
        }
        tOld = tNew; nOld = nNew; pCur = pNew;
        opPP = opP; opP = opN; ogP = ogN;

        asm volatile("s_waitcnt lgkmcnt(0)" ::: "memory");
        __builtin_amdgcn_s_barrier();
        __builtin_amdgcn_sched_barrier(0);
    }

    // ---- post-loop outputs ----
    if (w < 4 && lane < 16) {
        OUTPUT(nt - 2, (nt - 2) % 3, opPP, ogP);
        int ogLast = group_id[opP];
        OUTPUT(nt - 1, (nt - 1) % 3, opP, ogLast);
    }
#undef STAGE
#undef OUTPUT
}

// ------------------------------------------------------------------
__global__ void within_total_k(const float* __restrict__ group_sums,
                               const int* __restrict__ var_rowptr,
                               const float* __restrict__ counts,
                               float* __restrict__ within, float* __restrict__ total) {
    __shared__ float buf[256];
    int tid = threadIdx.x;
    float s = 0.f;
    for (int i = tid; i < VV; i += 256) s += counts[i];
    buf[tid] = s;
    __syncthreads();
    for (int off = 128; off > 0; off >>= 1) {
        if (tid < off) buf[tid] += buf[tid + off];
        __syncthreads();
    }
    if (tid == 0) total[0] = buf[0];
    for (int v = tid; v < VV; v += 256) {
        int gs = var_rowptr[v], ge = var_rowptr[v + 1];
        float r0 = 0.f, r1 = 0.f;
        for (int g = gs; g < ge; ++g) {
            r0 += group_sums[2 * g + 0];
            r1 += group_sums[2 * g + 1];
            within[2 * g + 0] = r0;
            within[2 * g + 1] = r1;
        }
    }
}

__global__ void final_k(const float* __restrict__ logprob, const float* __restrict__ within,
                        const int* __restrict__ group_id, const int* __restrict__ vog,
                        const float* __restrict__ counts, const float* __restrict__ total,
                        const int* __restrict__ place_idx, float* __restrict__ outp) {
    int p = blockIdx.x * blockDim.x + threadIdx.x;
    if (p >= PP) return;
    int g = group_id[p];
    int v = vog[g];
    float lc = logf(counts[v]) - logf(total[0]);
    int node = place_idx[p];
    atomicAdd(&outp[node * 2 + 0], logprob[p * 2 + 0] + within[g * 2 + 0] + lc);
    atomicAdd(&outp[node * 2 + 1], logprob[p * 2 + 1] + within[g * 2 + 1] + lc);
}

// ------------------------------------------------------------------
extern "C" void kernel_launch(void* const* d_in, const int* in_sizes, int n_in,
                              void* d_out, int out_size, void* d_ws, size_t ws_size,
                              hipStream_t stream) {
    const float* x          = (const float*)d_in[0];
    const float* W_enc_self = (const float*)d_in[1];
    const float* W_enc_nei  = (const float*)d_in[2];
    const float* b_enc      = (const float*)d_in[3];
    const float* W2_self    = (const float*)d_in[4];
    const float* W2_nei     = (const float*)d_in[5];
    const float* b2         = (const float*)d_in[6];
    const float* Wd1        = (const float*)d_in[7];
    const float* bd1        = (const float*)d_in[8];
    const float* Wd2        = (const float*)d_in[9];
    const float* bd2        = (const float*)d_in[10];
    const float* counts     = (const float*)d_in[11];
    const int* edge_src     = (const int*)d_in[12];
    const int* edge_dst     = (const int*)d_in[13];
    const int* place_idx    = (const int*)d_in[14];
    const int* src_idx      = (const int*)d_in[15];
    const int* t_idx        = (const int*)d_in[16];
    const int* dst_nodes    = (const int*)d_in[17];
    const int* dst_seg      = (const int*)d_in[18];
    const int* group_id     = (const int*)d_in[19];
    const int* variant_of_group = (const int*)d_in[20];
    float* outp = (float*)d_out;

    const int NB = (NN + 255) / 256;

    // ---- workspace layout ----
    unsigned short* rot0 = (unsigned short*)d_ws;               // N*H bf16
    unsigned short* rot1 = rot0 + (size_t)NN * HD;              // N*H bf16
    unsigned short* xb   = rot1 + (size_t)NN * HD;              // N*FIN bf16
    unsigned char* xbq   = (unsigned char*)(xb + (size_t)NN * FINN);  // N*FIN fp8
    unsigned char* featsq = xbq + (size_t)NN * FINN;            // 9*N*128 fp8
    unsigned char* dstcq  = featsq + (size_t)(TT + 1) * NN * HD; // P*128 fp8
    unsigned short* wenc_t = (unsigned short*)(dstcq + (size_t)PP * HD); // 128*128
    unsigned short* w2_t   = wenc_t + HD * 2 * FINN;            // 128*256
    unsigned short* wd1t   = w2_t + HD * 2 * HD;                // 384*384 bf16
    unsigned char* wd1tq   = (unsigned char*)(wd1t + 384 * 384);  // 384*384 fp8
    int* zr = (int*)(wd1tq + 384 * 384);
    int* csr_counts   = zr;                                     // N
    int* csr_cursor   = csr_counts + NN;                        // N
    float* group_sums = (float*)(csr_cursor + NN);              // 2G
    int* hist9        = (int*)(group_sums + 2 * GG);            // 9
    int* cursor9      = hist9 + 9;                              // 9
    size_t zero_words = (size_t)NN + NN + 2 * GG + 18;
    int* bsum       = cursor9 + 9;                              // 256
    int* boff       = bsum + 256;                               // 256
    int* boff9      = boff + 256;                               // 10 (+pad 6)
    int* csr_rowptr = boff9 + 16;                               // N+1
    int* dst_rowptr = csr_rowptr + (NN + 1);                    // P+1
    int* var_rowptr = dst_rowptr + (PP + 1);                    // V+1
    int* csr_src    = var_rowptr + (VV + 1);                    // E
    int* pperm      = csr_src + EE;                             // P
    float* logprob  = (float*)(pperm + PP);                     // 2P
    float* within   = logprob + 2 * PP;                         // 2G
    float* total_counts = within + 2 * GG;                      // 1

    hipMemsetAsync(zr, 0, zero_words * 4, stream);
    hipMemsetAsync(d_out, 0, (size_t)out_size * sizeof(float), stream);

    // ---- prep + CSR builds + t-bucket permutation ----
    prep_k<<<(NN * FINN + 255) / 256, 256, 0, stream>>>(x, W_enc_self, W_enc_nei, W2_self,
                                                        W2_nei, Wd1, xb, xbq, wenc_t, w2_t,
                                                        wd1t, wd1tq);
    count_k<<<(EE + 255) / 256, 256, 0, stream>>>(edge_dst, csr_counts, EE);
    blk_sum_k<<<NB, 256, 0, stream>>>(csr_counts, NN, bsum);
    scan_small_k<<<1, 256, 0, stream>>>(bsum, NB, boff);
    rowptr_fill_k<<<NB, 256, 0, stream>>>(csr_counts, boff, NN, csr_rowptr, EE);
    fill_csr_k<<<(EE + 255) / 256, 256, 0, stream>>>(edge_src, edge_dst, csr_rowptr,
                                                     csr_cursor, csr_src, EE);
    lb_rowptr_k<<<(PP + 256) / 256, 256, 0, stream>>>(dst_seg, DD, dst_rowptr, PP);
    lb_rowptr_k<<<(VV + 256) / 256, 256, 0, stream>>>(variant_of_group, GG, var_rowptr, VV);
    hist9_k<<<(PP + 255) / 256, 256, 0, stream>>>(t_idx, hist9);
    scan9_k<<<1, 64, 0, stream>>>(hist9, boff9);
    bucket_perm_k<<<(PP + 255) / 256, 256, 0, stream>>>(t_idx, boff9, cursor9, pperm);

    // ---- 9 fused MP rounds: fp8 gather in phase A, bf16 self in B ----
    const int NB32 = (NN + 31) / 32;
    for (int r = 0; r <= TT; ++r) {
        const unsigned short* hin = (r == 0) ? xb : ((r & 1) ? rot0 : rot1);
        const unsigned char* hinq = (r == 0) ? xbq : featsq + (size_t)(r - 1) * NN * HD;
        unsigned short* hout = (r & 1) ? rot1 : rot0;
        unsigned char* houtq = featsq + (size_t)r * NN * HD;
        if (r == 0)
            mpf2_k<FINN><<<NB32, 256, 0, stream>>>(hin, hinq, csr_rowptr, csr_src, wenc_t,
                                                   b_enc, hout, houtq);
        else
            mpf2_k<HD><<<NB32, 256, 0, stream>>>(hin, hinq, csr_rowptr, csr_src, w2_t,
                                                 b2, hout, houtq);
    }

    // ---- fp8 dst segment-sum + depth-3 native-fp8 dec11 ----
    dst_sum2q_k<<<(PP + 15) / 16, 256, 0, stream>>>(featsq, t_idx, dst_nodes, dst_rowptr,
                                                    pperm, dstcq);
    dec11_k<<<DEC_GRID, 512, 0, stream>>>(featsq, dstcq, place_idx, src_idx, t_idx,
                                          group_id, pperm, wd1tq, bd1, Wd2, bd2,
                                          logprob, group_sums);

    // ---- tail ----
    within_total_k<<<1, 256, 0, stream>>>(group_sums, var_rowptr, counts, within, total_counts);
    final_k<<<(PP + 255) / 256, 256, 0, stream>>>(logprob, within, group_id, variant_of_group,
                                                  counts, total_counts, place_idx, outp);
}